// Round 18
// baseline (539.083 us; speedup 1.0000x reference)
//
#include <hip/hip_runtime.h>

#define D 256
#define BM 128
#define BN 128
#define BK 64
#define SCAN_NB 64
#define SCAN_T (SCAN_NB * 256)

typedef __attribute__((ext_vector_type(8))) short bf16x8;
typedef __attribute__((ext_vector_type(4))) float f32x4;
typedef __attribute__((ext_vector_type(4))) unsigned int u32x4;

union frag_cvt { u32x4 u; bf16x8 h; };

__device__ __forceinline__ unsigned short bf16_rn(float f) {
    const unsigned int u = __float_as_uint(f);
    return (unsigned short)((u + 0x7FFFu + ((u >> 16) & 1u)) >> 16);
}
__device__ __forceinline__ float bf16_to_f32(unsigned short s) {
    return __uint_as_float(((unsigned int)s) << 16);
}
// bijective XCD-chunk remap (m204)
__device__ __forceinline__ int xcd_logical(int bx, int NB) {
    const int q = NB >> 3, rem = NB & 7;
    const int xcd = bx & 7, slot = bx >> 3;
    return (xcd < rem) ? xcd * (q + 1) + slot
                       : rem * (q + 1) + (xcd - rem) * q + slot;
}

// ---------------- merged weight precompute, phase 1 ----------------
__global__ __launch_bounds__(256) void pre1_kernel(
    const float* __restrict__ W_in, const float* __restrict__ lA, const float* __restrict__ lB,
    unsigned short* __restrict__ win_eff,
    const float* __restrict__ W_self, unsigned short* __restrict__ ws0,
    const float* __restrict__ W_neigh, unsigned short* __restrict__ wn0,
    const float* __restrict__ Wo, const float* __restrict__ Wv, float* __restrict__ wvo,
    const float* __restrict__ bvp, const float* __restrict__ bo, float* __restrict__ bvo)
{
    const int b = blockIdx.x, tid = threadIdx.x;
    if (b < 512) {
        const int t = b >> 8, o = b & 255;
        float acc = W_in[((size_t)t * D + o) * D + tid];
        const float* Br = lB + ((size_t)t * D + o) * 16;
        const float* At = lA + (size_t)t * 16 * D;
        #pragma unroll
        for (int r = 0; r < 16; ++r) acc = fmaf(Br[r], At[r * D + tid], acc);
        win_eff[((size_t)t * D + o) * D + tid] = bf16_rn(acc);
    } else if (b < 1024) {
        const int i = (b - 512) * 256 + tid;
        ws0[i] = bf16_rn(W_self[i]);
    } else if (b < 1536) {
        const int i = (b - 1024) * 256 + tid;
        wn0[i] = bf16_rn(W_neigh[i]);
    } else if (b < 2048) {
        const int t = (b - 1536) >> 8, p = (b - 1536) & 255;
        const float* Xr = Wo + ((size_t)t * D + p) * D;
        const float* Yt = Wv + (size_t)t * D * D;
        float acc = 0.f;
        for (int o = 0; o < D; ++o) acc = fmaf(Xr[o], Yt[(size_t)o * D + tid], acc);
        wvo[((size_t)t * D + p) * D + tid] = acc;
    } else {
        const int t = b - 2048;
        const float* Mr = Wo + ((size_t)t * D + tid) * D;
        const float* vr = bvp + (size_t)t * D;
        float acc = bo[(size_t)t * D + tid];
        for (int o = 0; o < D; ++o) acc = fmaf(Mr[o], vr[o], acc);
        bvo[(size_t)t * D + tid] = acc;
    }
}

// ---------------- merged weight precompute, phase 2 (needs wvo) ----------------
__global__ __launch_bounds__(256) void pre2_kernel(
    const float* __restrict__ wvo,
    const float* __restrict__ W_self1, unsigned short* __restrict__ ws1,
    const float* __restrict__ W_neigh1, unsigned short* __restrict__ wn1,
    const float* __restrict__ b_sage1, const float* __restrict__ bvo, float* __restrict__ b1e)
{
    const int b = blockIdx.x, tid = threadIdx.x;
    if (b < 512) {
        const int t = b >> 8, p = b & 255;
        const float* Xr = wvo + ((size_t)t * D + p) * D;
        const float* Yt = W_self1 + (size_t)t * D * D;
        float acc = 0.f;
        for (int o = 0; o < D; ++o) acc = fmaf(Xr[o], Yt[(size_t)o * D + tid], acc);
        ws1[((size_t)t * D + p) * D + tid] = bf16_rn(acc);
    } else if (b < 1024) {
        const int t = (b - 512) >> 8, p = (b - 512) & 255;
        const float* Xr = wvo + ((size_t)t * D + p) * D;
        const float* Yt = W_neigh1 + (size_t)t * D * D;
        float acc = 0.f;
        for (int o = 0; o < D; ++o) acc = fmaf(Xr[o], Yt[(size_t)o * D + tid], acc);
        wn1[((size_t)t * D + p) * D + tid] = bf16_rn(acc);
    } else {
        const int t = b - 1024;
        const float* Mr = wvo + ((size_t)t * D + tid) * D;
        const float* vr = b_sage1 + (size_t)t * D;
        float acc = bvo[(size_t)t * D + tid];
        for (int o = 0; o < D; ++o) acc = fmaf(Mr[o], vr[o], acc);
        b1e[(size_t)t * D + tid] = acc;
    }
}

// ---------------- B fragments for one 128-wide K-half (L2-resident W) ----------------
__device__ __forceinline__ void load_bfrag(const unsigned short* __restrict__ Wp,
                                           int n0, int wn, int cidx, int rgrp,
                                           int kh, bf16x8 (&bq)[4][4])
{
    #pragma unroll
    for (int n = 0; n < 4; ++n) {
        const int o = n0 + wn + n * 16 + cidx;
        #pragma unroll
        for (int kk = 0; kk < 4; ++kk) {
            frag_cvt c;
            c.u = *(const u32x4*)(Wp + (size_t)o * D + kh * 128 + kk * 32 + rgrp * 8);
            bq[n][kk] = c.h;
        }
    }
}

// ---------------- 128-row A tile -> LDS via global_load_lds (pre-swizzled source) ----------------
__device__ __forceinline__ void gload_tile(const unsigned short* __restrict__ Abase,
                                           int r0, int kt, int tid, char* lbuf)
{
    const int wbase = (tid >> 6) << 10;   // wave-uniform 1KB sub-block
    #pragma unroll
    for (int c = 0; c < 4; ++c) {
        const int p   = c * 4096 + tid * 16;     // physical LDS byte offset
        const int row = p >> 7;                  // 128 B per row (64 bf16)
        const int lwb = p & 127;
        const int lg  = lwb ^ ((row & 7) << 4);  // logical within-row byte
        const unsigned short* g = Abase + (size_t)(r0 + row) * D + kt + (lg >> 1);
        char* l = lbuf + c * 4096 + wbase;       // wave-uniform
        __builtin_amdgcn_global_load_lds(
            (const __attribute__((address_space(1))) unsigned int*)g,
            (__attribute__((address_space(3))) unsigned int*)l, 16, 0, 0);
    }
}

// ======== layer GEMM: Cbf = bf16( A.W1^T + A2[swap].W2^T + bias ) ========
// COMBO: r14's counted-vmcnt depth-2 pipeline (raw s_barrier, vmcnt(4), 3 LDS
// buffers) + r17's XCD pairing (twin n-tiles of an m-panel co-reside on one
// XCD -> prefetched A loads are L2-hits, coverable by the depth-2 window).
__global__ __launch_bounds__(256, 2) void gemm_bf16_kernel(
    const unsigned short* __restrict__ A, const unsigned short* __restrict__ W1,
    const unsigned short* __restrict__ A2, const unsigned short* __restrict__ W2,
    const float* __restrict__ bias,
    unsigned short* __restrict__ Cbf, int M, int swap2)
{
    const int t   = blockIdx.z;
    const int logical = xcd_logical(blockIdx.x, gridDim.x);
    const int m0  = (logical >> 1) * BM;
    const int n0  = (logical & 1) * BN;
    const int tid = threadIdx.x;
    const int lane = tid & 63;
    const int wid  = tid >> 6;
    const int wm = (wid >> 1) * 64;
    const int wn = (wid & 1) * 64;
    const int rgrp = lane >> 4;
    const int cidx = lane & 15;

    __shared__ __align__(16) unsigned short SH[24576];   // 48 KB: 3 A buffers ∪ C half-stage
    char* const AB[3] = { (char*)SH, (char*)SH + 16384, (char*)SH + 32768 };

    const int t2 = swap2 ? (1 - t) : t;
    const unsigned short* Aps[2] = { A  + (size_t)t  * M * D, A2 + (size_t)t2 * M * D };
    const unsigned short* Wps[2] = { W1 + (size_t)t  * D * D, W2 + (size_t)t  * D * D };

    f32x4 acc[4][4];
    #pragma unroll
    for (int i = 0; i < 4; ++i)
        #pragma unroll
        for (int j = 0; j < 4; ++j)
            acc[i][j] = (f32x4){0.f, 0.f, 0.f, 0.f};

    bf16x8 bq[2][4][4];
    // prologue issue order: G0, F0, G1  (per-thread FIFO analyzed in r14)
    gload_tile(Aps[0], m0, 0, tid, AB[0]);
    load_bfrag(Wps[0], n0, wn, cidx, rgrp, 0, bq[0]);
    gload_tile(Aps[0], m0, BK, tid, AB[1]);

    #pragma unroll
    for (int idx = 0; idx < 8; ++idx) {
        __builtin_amdgcn_sched_barrier(0);
        if (idx < 7) asm volatile("s_waitcnt vmcnt(4)" ::: "memory");
        else         asm volatile("s_waitcnt vmcnt(0)" ::: "memory");
        __builtin_amdgcn_s_barrier();
        __builtin_amdgcn_sched_barrier(0);
        if ((idx & 1) == 1 && idx < 7) {
            const int nh = (idx >> 1) + 1;          // next K-half 1..3
            load_bfrag(Wps[nh >> 1], n0, wn, cidx, rgrp, nh & 1, bq[nh & 1]);
        }
        if (idx < 6) {
            const int nt = idx + 2;                 // depth-2 prefetch (L2-hit via pairing)
            gload_tile(Aps[nt >> 2], m0, (nt & 3) * BK, tid, AB[nt % 3]);
        }
        const char* cb = AB[idx % 3];
        const int half = idx >> 1;
        #pragma unroll
        for (int ks = 0; ks < 2; ++ks) {
            const int kb = ks * 64 + rgrp * 16;
            bf16x8 af[4];
            #pragma unroll
            for (int m = 0; m < 4; ++m) {
                const int row = wm + m * 16 + cidx;
                const int sw  = (row * 128 + kb) ^ ((row & 7) << 4);
                frag_cvt c; c.u = *(const u32x4*)(cb + sw); af[m] = c.h;
            }
            #pragma unroll
            for (int m = 0; m < 4; ++m)
                #pragma unroll
                for (int n = 0; n < 4; ++n)
                    acc[m][n] = __builtin_amdgcn_mfma_f32_16x16x32_bf16(
                        af[m], bq[half & 1][n][(idx & 1) * 2 + ks], acc[m][n], 0, 0, 0);
        }
    }

    // ---- epilogue: two 64-row halves through LDS, coalesced stores ----
    unsigned short* Ct = Cbf + (size_t)t * M * D;
    #pragma unroll
    for (int h = 0; h < 2; ++h) {
        __syncthreads();
        if ((wid >> 1) == h) {
            #pragma unroll
            for (int n = 0; n < 4; ++n) {
                const int col = wn + n * 16 + cidx;
                const float bc = bias[t * D + n0 + col];
                #pragma unroll
                for (int m = 0; m < 4; ++m) {
                    const int rw = (wm & 63) + m * 16 + rgrp * 4;
                    #pragma unroll
                    for (int i = 0; i < 4; ++i)
                        SH[(rw + i) * 136 + col] = bf16_rn(acc[m][n][i] + bc);
                }
            }
        }
        __syncthreads();
        #pragma unroll
        for (int it = 0; it < 2; ++it) {
            const int g   = tid + it * 256;
            const int row = g >> 3;         // 0..63
            const int cg  = g & 7;
            const int grow = m0 + h * 64 + row;
            if (grow < M) {
                const u32x4 lo = *(const u32x4*)&SH[row * 136 + cg * 16];
                const u32x4 hi = *(const u32x4*)&SH[row * 136 + cg * 16 + 8];
                u32x4* dst = (u32x4*)(Ct + (size_t)grow * D + n0 + cg * 16);
                dst[0] = lo;
                dst[1] = hi;
            }
        }
    }
}

// ======== input GEMM: BM=64, 128 threads, (128,2); XCD-paired n-tiles ========
__global__ __launch_bounds__(128, 2) void gemm_in_kernel(
    const float* __restrict__ X, const unsigned short* __restrict__ Wb,
    const float* __restrict__ bias, unsigned short* __restrict__ Cbf, int M)
{
    const int t   = blockIdx.z;
    const int logical = xcd_logical(blockIdx.x, gridDim.x);
    const int m0  = (logical >> 1) * 64;
    const int n0  = (logical & 1) * BN;
    const int tid = threadIdx.x;
    const int lane = tid & 63;
    const int wid  = tid >> 6;
    const int wn = wid * 64;
    const int rgrp = lane >> 4;
    const int cidx = lane & 15;

    __shared__ __align__(16) unsigned short SH[8704];   // 17.4 KB: Ah(8K)+Al(8K) ∪ C stage
    char* AhB = (char*)SH;
    char* AlB = (char*)SH + 8192;

    const float* Xp = X + (size_t)t * M * D;
    const unsigned short* Wp = Wb + (size_t)t * D * D;

    f32x4 acc[4][4];
    #pragma unroll
    for (int i = 0; i < 4; ++i)
        #pragma unroll
        for (int j = 0; j < 4; ++j)
            acc[i][j] = (f32x4){0.f, 0.f, 0.f, 0.f};

    bf16x8 bq[2][4][4];
    float4 xr0[4], xr1[4];
    #pragma unroll
    for (int it = 0; it < 4; ++it) {
        const int g = tid + it * 128;     // 0..511
        const int row = g >> 3;           // 0..63
        const int kg = g & 7;
        const int ar = min(m0 + row, M - 1);   // clamp: X is an input buffer
        xr0[it] = *(const float4*)(Xp + (size_t)ar * D + kg * 8);
        xr1[it] = *(const float4*)(Xp + (size_t)ar * D + kg * 8 + 4);
    }
    load_bfrag(Wp, n0, wn, cidx, rgrp, 0, bq[0]);

    #pragma unroll
    for (int kt_i = 0; kt_i < 4; ++kt_i) {
        #pragma unroll
        for (int it = 0; it < 4; ++it) {
            const int g = tid + it * 128;
            const int row = g >> 3;
            const int kg = g & 7;
            float v[8] = { xr0[it].x, xr0[it].y, xr0[it].z, xr0[it].w,
                           xr1[it].x, xr1[it].y, xr1[it].z, xr1[it].w };
            unsigned int hi[4], lo[4];
            #pragma unroll
            for (int j = 0; j < 4; ++j) {
                const unsigned int ua = __float_as_uint(v[2*j]);
                const unsigned int ub = __float_as_uint(v[2*j+1]);
                hi[j] = (ub & 0xFFFF0000u) | (ua >> 16);
                const float ra = v[2*j]   - __uint_as_float(ua & 0xFFFF0000u);
                const float rb = v[2*j+1] - __uint_as_float(ub & 0xFFFF0000u);
                lo[j] = (__float_as_uint(rb) & 0xFFFF0000u) | (__float_as_uint(ra) >> 16);
            }
            const int sw = ((row * BK + kg * 8) * 2) ^ ((row & 7) << 4);
            *(u32x4*)(AhB + sw) = (u32x4){hi[0], hi[1], hi[2], hi[3]};
            *(u32x4*)(AlB + sw) = (u32x4){lo[0], lo[1], lo[2], lo[3]};
        }
        __syncthreads();
        if (kt_i < 3) {
            const int kt = (kt_i + 1) * BK;
            #pragma unroll
            for (int it = 0; it < 4; ++it) {
                const int g = tid + it * 128;
                const int row = g >> 3;
                const int kg = g & 7;
                const int ar = min(m0 + row, M - 1);
                xr0[it] = *(const float4*)(Xp + (size_t)ar * D + kt + kg * 8);
                xr1[it] = *(const float4*)(Xp + (size_t)ar * D + kt + kg * 8 + 4);
            }
        }
        if (kt_i == 1) load_bfrag(Wp, n0, wn, cidx, rgrp, 1, bq[1]);  // for kt_i=2,3
        #pragma unroll
        for (int ks = 0; ks < 2; ++ks) {
            const int kb = ks * 64 + rgrp * 16;
            bf16x8 afh[4], afl[4];
            #pragma unroll
            for (int m = 0; m < 4; ++m) {
                const int row = m * 16 + cidx;
                const int sw  = (row * 128 + kb) ^ ((row & 7) << 4);
                frag_cvt c1; c1.u = *(u32x4*)(AhB + sw); afh[m] = c1.h;
                frag_cvt c2; c2.u = *(u32x4*)(AlB + sw); afl[m] = c2.h;
            }
            #pragma unroll
            for (int m = 0; m < 4; ++m)
                #pragma unroll
                for (int n = 0; n < 4; ++n) {
                    const bf16x8 bfr = bq[kt_i >> 1][n][(kt_i & 1) * 2 + ks];
                    acc[m][n] = __builtin_amdgcn_mfma_f32_16x16x32_bf16(afh[m], bfr, acc[m][n], 0, 0, 0);
                    acc[m][n] = __builtin_amdgcn_mfma_f32_16x16x32_bf16(afl[m], bfr, acc[m][n], 0, 0, 0);
                }
        }
        __syncthreads();
    }

    #pragma unroll
    for (int n = 0; n < 4; ++n) {
        const int col = wn + n * 16 + cidx;
        const float bc = bias[t * D + n0 + col];
        #pragma unroll
        for (int m = 0; m < 4; ++m) {
            const int rowb = m * 16 + rgrp * 4;
            #pragma unroll
            for (int i = 0; i < 4; ++i)
                SH[(rowb + i) * 136 + col] = bf16_rn(acc[m][n][i] + bc);
        }
    }
    __syncthreads();
    unsigned short* Ct = Cbf + (size_t)t * M * D;
    #pragma unroll
    for (int it = 0; it < 4; ++it) {
        const int g   = tid + it * 128;
        const int row = g >> 3;
        const int cg  = g & 7;
        const int grow = m0 + row;
        if (grow < M) {
            const u32x4 lo = *(const u32x4*)&SH[row * 136 + cg * 16];
            const u32x4 hi = *(const u32x4*)&SH[row * 136 + cg * 16 + 8];
            u32x4* dst = (u32x4*)(Ct + (size_t)grow * D + n0 + cg * 16);
            dst[0] = lo;
            dst[1] = hi;
        }
    }
}

// ---------------- LayerNorm, one wave per row; bf16 in/res/out ----------------
__global__ __launch_bounds__(256) void ln_wave_kernel(
    const unsigned short* __restrict__ in_bf, const unsigned short* __restrict__ res_bf,
    const float* __restrict__ g, const float* __restrict__ b,
    unsigned short* __restrict__ out_bf, int N)
{
    const int row  = (blockIdx.x * 256 + threadIdx.x) >> 6;
    const int lane = threadIdx.x & 63;
    if (row >= 2 * N) return;
    const int t = (row >= N) ? 1 : 0;
    const ushort4 iv = *(const ushort4*)(in_bf + (size_t)row * D + lane * 4);
    float4 v = make_float4(bf16_to_f32(iv.x), bf16_to_f32(iv.y),
                           bf16_to_f32(iv.z), bf16_to_f32(iv.w));
    if (res_bf) {
        const ushort4 rv = *(const ushort4*)(res_bf + (size_t)row * D + lane * 4);
        v.x += bf16_to_f32(rv.x); v.y += bf16_to_f32(rv.y);
        v.z += bf16_to_f32(rv.z); v.w += bf16_to_f32(rv.w);
    }
    float s = v.x + v.y + v.z + v.w;
    #pragma unroll
    for (int off = 32; off > 0; off >>= 1) s += __shfl_xor(s, off);
    const float mu = s * (1.0f / 256.0f);
    const float4 dl = make_float4(v.x - mu, v.y - mu, v.z - mu, v.w - mu);
    float q = dl.x * dl.x + dl.y * dl.y + dl.z * dl.z + dl.w * dl.w;
    #pragma unroll
    for (int off = 32; off > 0; off >>= 1) q += __shfl_xor(q, off);
    const float rstd = rsqrtf(q * (1.0f / 256.0f) + 1e-5f);
    const float4 gv = *(const float4*)(g + (size_t)t * D + lane * 4);
    const float4 bv = *(const float4*)(b + (size_t)t * D + lane * 4);
    ushort4 ob;
    ob.x = bf16_rn(dl.x * rstd * gv.x + bv.x);
    ob.y = bf16_rn(dl.y * rstd * gv.y + bv.y);
    ob.z = bf16_rn(dl.z * rstd * gv.z + bv.z);
    ob.w = bf16_rn(dl.w * rstd * gv.w + bv.w);
    *(ushort4*)(out_bf + (size_t)row * D + lane * 4) = ob;
}

// ---------------- CSR build ----------------
__global__ void count_kernel(const int* __restrict__ e_dst, int* __restrict__ cnt,
                             int E2, int N, int E)
{
    const int i = blockIdx.x * 256 + threadIdx.x;
    if (i >= E2) return;
    const int t = i / E;
    atomicAdd(&cnt[(size_t)t * N + e_dst[i]], 1);
}

__global__ __launch_bounds__(256) void scan1_kernel(const int* __restrict__ cnt,
                                                    int* __restrict__ texcl,
                                                    int* __restrict__ bsum, int n, int c)
{
    __shared__ int ts[256];
    const int tid = threadIdx.x;
    const int gt  = blockIdx.x * 256 + tid;
    const int b   = gt * c;
    const int e   = min(b + c, n);
    int s = 0;
    for (int i = b; i < e; ++i) s += cnt[i];
    ts[tid] = s;
    __syncthreads();
    #pragma unroll
    for (int off = 1; off < 256; off <<= 1) {
        const int v = (tid >= off) ? ts[tid - off] : 0;
        __syncthreads();
        ts[tid] += v;
        __syncthreads();
    }
    texcl[gt] = ts[tid] - s;
    if (tid == 255) bsum[blockIdx.x] = ts[255];
}

__global__ __launch_bounds__(64) void scan2_kernel(int* __restrict__ bsum,
                                                   int* __restrict__ bbase,
                                                   int* __restrict__ offs, int n, int nb)
{
    const int lane = threadIdx.x;
    int v = (lane < nb) ? bsum[lane] : 0;
    int s = v;
    #pragma unroll
    for (int off = 1; off < 64; off <<= 1) {
        const int u = __shfl_up(s, off);
        if (lane >= off) s += u;
    }
    if (lane < nb) bbase[lane] = s - v;
    if (lane == 63) offs[n] = s;
}

__global__ __launch_bounds__(256) void scan3_kernel(const int* __restrict__ cnt,
                                                    const int* __restrict__ texcl,
                                                    const int* __restrict__ bbase,
                                                    int* __restrict__ offs, int n, int c)
{
    const int tid = threadIdx.x;
    const int gt  = blockIdx.x * 256 + tid;
    const int b   = gt * c;
    const int e   = min(b + c, n);
    int base = bbase[blockIdx.x] + texcl[gt];
    for (int i = b; i < e; ++i) { offs[i] = base; base += cnt[i]; }
}

__global__ void fill_kernel(const int* __restrict__ e_src, const int* __restrict__ e_dst,
                            const int* __restrict__ offs, int* __restrict__ cur,
                            int* __restrict__ sorted, int E2, int N, int E)
{
    const int i = blockIdx.x * 256 + threadIdx.x;
    if (i >= E2) return;
    const int t = i / E;
    const int idx = t * N + e_dst[i];
    const int pos = offs[idx] + atomicAdd(&cur[idx], 1);
    sorted[pos] = e_src[i];
}

// ---------------- aggregation: one wave per (t,dst), bf16 gather + mean (2-way MLP) ----------------
__global__ __launch_bounds__(256) void agg_kernel(
    const unsigned short* __restrict__ hbf, const int* __restrict__ sorted_src,
    const int* __restrict__ offs, unsigned short* __restrict__ aggbf, int N)
{
    const int gw   = (blockIdx.x * 256 + threadIdx.x) >> 6;
    const int lane = threadIdx.x & 63;
    if (gw >= 2 * N) return;
    const int t = (gw >= N) ? 1 : 0;
    const int beg = offs[gw];
    const int end = offs[gw + 1];
    const unsigned short* hb = hbf + (size_t)t * N * D;
    float4 a0 = make_float4(0.f, 0.f, 0.f, 0.f);
    float4 a1 = make_float4(0.f, 0.f, 0.f, 0.f);
    int e = beg;
    for (; e + 2 <= end; e += 2) {
        const int s0 = sorted_src[e];
        const int s1 = sorted_src[e + 1];
        const ushort4 v0 = *(const ushort4*)(hb + (size_t)s0 * D + lane * 4);
        const ushort4 v1 = *(const ushort4*)(hb + (size_t)s1 * D + lane * 4);
        a0.x += bf16_to_f32(v0.x); a0.y += bf16_to_f32(v0.y);
        a0.z += bf16_to_f32(v0.z); a0.w += bf16_to_f32(v0.w);
        a1.x += bf16_to_f32(v1.x); a1.y += bf16_to_f32(v1.y);
        a1.z += bf16_to_f32(v1.z); a1.w += bf16_to_f32(v1.w);
    }
    if (e < end) {
        const int s0 = sorted_src[e];
        const ushort4 v0 = *(const ushort4*)(hb + (size_t)s0 * D + lane * 4);
        a0.x += bf16_to_f32(v0.x); a0.y += bf16_to_f32(v0.y);
        a0.z += bf16_to_f32(v0.z); a0.w += bf16_to_f32(v0.w);
    }
    const float inv = 1.0f / fmaxf((float)(end - beg), 1.0f);
    ushort4 o;
    o.x = bf16_rn((a0.x + a1.x) * inv); o.y = bf16_rn((a0.y + a1.y) * inv);
    o.z = bf16_rn((a0.z + a1.z) * inv); o.w = bf16_rn((a0.w + a1.w) * inv);
    *(ushort4*)(aggbf + (size_t)gw * D + lane * 4) = o;
}

// ---------------- scores (bf16 h, fp32 accumulate) ----------------
__global__ __launch_bounds__(256) void score_kernel(
    const unsigned short* __restrict__ h,
    const int* __restrict__ pos_src, const int* __restrict__ pos_dst,
    const int* __restrict__ neg_src, const int* __restrict__ neg_dst,
    float* __restrict__ out, int EP, int N)
{
    const int wid  = (blockIdx.x * 256 + threadIdx.x) >> 6;
    const int lane = threadIdx.x & 63;
    if (wid >= 2 * EP) return;
    const int kind = wid / EP;
    const int k    = wid - kind * EP;
    const int s = kind ? neg_src[k] : pos_src[k];
    const int d = kind ? neg_dst[k] : pos_dst[k];
    const ushort4 a = *(const ushort4*)(h + (size_t)s * D + lane * 4);
    const ushort4 b = *(const ushort4*)(h + ((size_t)N + d) * D + lane * 4);
    float v = bf16_to_f32(a.x) * bf16_to_f32(b.x)
            + bf16_to_f32(a.y) * bf16_to_f32(b.y)
            + bf16_to_f32(a.z) * bf16_to_f32(b.z)
            + bf16_to_f32(a.w) * bf16_to_f32(b.w);
    #pragma unroll
    for (int off = 32; off > 0; off >>= 1) v += __shfl_down(v, off);
    if (lane == 0) out[wid] = v;
}

extern "C" void kernel_launch(void* const* d_in, const int* in_sizes, int n_in,
                              void* d_out, int out_size, void* d_ws, size_t ws_size,
                              hipStream_t stream)
{
    const float* x      = (const float*)d_in[0];
    const float* W_in   = (const float*)d_in[1];
    const float* b_in   = (const float*)d_in[2];
    const float* lora_A = (const float*)d_in[3];
    const float* lora_B = (const float*)d_in[4];
    const float* pn_g   = (const float*)d_in[5];
    const float* pn_b   = (const float*)d_in[6];
    const float* W_self = (const float*)d_in[7];
    const float* W_neigh= (const float*)d_in[8];
    const float* b_sage = (const float*)d_in[9];
    const float* ln_g   = (const float*)d_in[10];
    const float* ln_b   = (const float*)d_in[11];
    const float* Wv     = (const float*)d_in[12];
    const float* bvp    = (const float*)d_in[13];
    const float* Wo     = (const float*)d_in[14];
    const float* bo     = (const float*)d_in[15];
    const int* e_src    = (const int*)d_in[16];
    const int* e_dst    = (const int*)d_in[17];
    const int* pos_src  = (const int*)d_in[18];
    const int* pos_dst  = (const int*)d_in[19];
    const int* neg_src  = (const int*)d_in[20];
    const int* neg_dst  = (const int*)d_in[21];

    const int N  = in_sizes[0] / (2 * D);
    const int E  = in_sizes[16] / 2;
    const int EP = in_sizes[18];
    const size_t ND2 = (size_t)2 * N * D;
    const size_t DD2 = (size_t)2 * D * D;
    const int n2 = 2 * N;

    unsigned short* P0 = (unsigned short*)d_ws;
    unsigned short* P1 = P0 + ND2;
    unsigned short* P2 = P1 + ND2;
    unsigned short* T  = P2 + ND2;
    int* cnt    = (int*)(T + ND2);
    int* cur    = cnt + (size_t)n2;          // adjacent to cnt -> single memset
    int* offs   = cur + (size_t)n2;          // n2+1
    int* sorted = offs + (size_t)n2 + 1;
    int* texcl  = sorted + (size_t)2 * E;
    int* bsum   = texcl + SCAN_T;
    int* bbase  = bsum + SCAN_NB;
    float* wvo  = (float*)(bbase + SCAN_NB);
    float* bvo  = wvo + DD2;
    float* b1e  = bvo + 2 * D;
    unsigned short* win_eff = (unsigned short*)(b1e + 2 * D);
    unsigned short* ws0 = win_eff + DD2;
    unsigned short* wn0 = ws0 + DD2;
    unsigned short* ws1 = wn0 + DD2;
    unsigned short* wn1 = ws1 + DD2;

    // ---- weight precompute: 2 merged dispatches ----
    pre1_kernel<<<2050, 256, 0, stream>>>(W_in, lora_A, lora_B, win_eff,
                                          W_self, ws0, W_neigh, wn0,
                                          Wo, Wv, wvo, bvp, bo, bvo);
    pre2_kernel<<<1026, 256, 0, stream>>>(wvo, W_self + DD2, ws1,
                                          W_neigh + DD2, wn1,
                                          b_sage + 2 * D, bvo, b1e);

    // ---- CSR build (edges shared by both layers) ----
    hipMemsetAsync(cnt, 0, (size_t)2 * n2 * sizeof(int), stream);   // cnt + cur
    count_kernel<<<(2 * E + 255) / 256, 256, 0, stream>>>(e_dst, cnt, 2 * E, N, E);
    const int sc = (n2 + SCAN_T - 1) / SCAN_T;
    scan1_kernel<<<SCAN_NB, 256, 0, stream>>>(cnt, texcl, bsum, n2, sc);
    scan2_kernel<<<1, 64, 0, stream>>>(bsum, bbase, offs, n2, SCAN_NB);
    scan3_kernel<<<SCAN_NB, 256, 0, stream>>>(cnt, texcl, bbase, offs, n2, sc);
    fill_kernel<<<(2 * E + 255) / 256, 256, 0, stream>>>(e_src, e_dst, offs, cur, sorted, 2 * E, N, E);

    const dim3 gblk128(128);
    const dim3 gblk(256);
    const int mpan_l = (N + BM - 1) / BM;               // 391
    const int mpan_i = (N + 63) / 64;                   // 782
    const dim3 ggrid(2 * mpan_l, 1, 2);                 // layer GEMM: XCD-paired 1-D
    const dim3 ggrid_in(2 * mpan_i, 1, 2);              // input GEMM: XCD-paired 1-D
    const int ln_grid = (2 * N + 3) / 4;

    // ---- input projection (exact fp32 via in-kernel hi/lo split) -> T ; prenorm -> P0 ----
    gemm_in_kernel<<<ggrid_in, gblk128, 0, stream>>>(x, win_eff, b_in, T, N);
    ln_wave_kernel<<<ln_grid, gblk, 0, stream>>>(T, nullptr, pn_g, pn_b, P0, N);

    // ---- layer 0: agg(P0)->P1 ; GEMM -> T ; LN -> P2 ----
    agg_kernel<<<dim3((2 * N + 3) / 4, 1, 1), gblk, 0, stream>>>(P0, sorted, offs, P1, N);
    gemm_bf16_kernel<<<ggrid, gblk, 0, stream>>>(P0, ws0, P1, wn0, b_sage, T, N, 1);
    ln_wave_kernel<<<ln_grid, gblk, 0, stream>>>(T, nullptr, ln_g, ln_b, P2, N);

    // ---- layer 1 (Wv/Wo folded): agg(P2)->P1 ; GEMM -> T ; LN(+res=P2) -> P0 ----
    agg_kernel<<<dim3((2 * N + 3) / 4, 1, 1), gblk, 0, stream>>>(P2, sorted, offs, P1, N);
    gemm_bf16_kernel<<<ggrid, gblk, 0, stream>>>(P2, ws1, P1, wn1, b1e, T, N, 1);
    ln_wave_kernel<<<ln_grid, gblk, 0, stream>>>(T, P2, ln_g + 2 * D, ln_b + 2 * D, P0, N);

    score_kernel<<<(2 * EP + 3) / 4, gblk, 0, stream>>>(P0, pos_src, pos_dst, neg_src, neg_dst,
                                                        (float*)d_out, EP, N);
}

// Round 19
// 529.669 us; speedup vs baseline: 1.0178x; 1.0178x over previous
//
#include <hip/hip_runtime.h>

#define D 256
#define BM 128
#define BN 128
#define BK 64
#define SCAN_NB 64
#define SCAN_T (SCAN_NB * 256)

typedef __attribute__((ext_vector_type(8))) short bf16x8;
typedef __attribute__((ext_vector_type(4))) float f32x4;
typedef __attribute__((ext_vector_type(4))) unsigned int u32x4;

union frag_cvt { u32x4 u; bf16x8 h; };

__device__ __forceinline__ unsigned short bf16_rn(float f) {
    const unsigned int u = __float_as_uint(f);
    return (unsigned short)((u + 0x7FFFu + ((u >> 16) & 1u)) >> 16);
}
__device__ __forceinline__ float bf16_to_f32(unsigned short s) {
    return __uint_as_float(((unsigned int)s) << 16);
}
// bijective XCD-chunk remap (m204)
__device__ __forceinline__ int xcd_logical(int bx, int NB) {
    const int q = NB >> 3, rem = NB & 7;
    const int xcd = bx & 7, slot = bx >> 3;
    return (xcd < rem) ? xcd * (q + 1) + slot
                       : rem * (q + 1) + (xcd - rem) * q + slot;
}

// ---------------- merged weight precompute, phase 1 ----------------
__global__ __launch_bounds__(256) void pre1_kernel(
    const float* __restrict__ W_in, const float* __restrict__ lA, const float* __restrict__ lB,
    unsigned short* __restrict__ win_eff,
    const float* __restrict__ W_self, unsigned short* __restrict__ ws0,
    const float* __restrict__ W_neigh, unsigned short* __restrict__ wn0,
    const float* __restrict__ Wo, const float* __restrict__ Wv, float* __restrict__ wvo,
    const float* __restrict__ bvp, const float* __restrict__ bo, float* __restrict__ bvo)
{
    const int b = blockIdx.x, tid = threadIdx.x;
    if (b < 512) {
        const int t = b >> 8, o = b & 255;
        float acc = W_in[((size_t)t * D + o) * D + tid];
        const float* Br = lB + ((size_t)t * D + o) * 16;
        const float* At = lA + (size_t)t * 16 * D;
        #pragma unroll
        for (int r = 0; r < 16; ++r) acc = fmaf(Br[r], At[r * D + tid], acc);
        win_eff[((size_t)t * D + o) * D + tid] = bf16_rn(acc);
    } else if (b < 1024) {
        const int i = (b - 512) * 256 + tid;
        ws0[i] = bf16_rn(W_self[i]);
    } else if (b < 1536) {
        const int i = (b - 1024) * 256 + tid;
        wn0[i] = bf16_rn(W_neigh[i]);
    } else if (b < 2048) {
        const int t = (b - 1536) >> 8, p = (b - 1536) & 255;
        const float* Xr = Wo + ((size_t)t * D + p) * D;
        const float* Yt = Wv + (size_t)t * D * D;
        float acc = 0.f;
        for (int o = 0; o < D; ++o) acc = fmaf(Xr[o], Yt[(size_t)o * D + tid], acc);
        wvo[((size_t)t * D + p) * D + tid] = acc;
    } else {
        const int t = b - 2048;
        const float* Mr = Wo + ((size_t)t * D + tid) * D;
        const float* vr = bvp + (size_t)t * D;
        float acc = bo[(size_t)t * D + tid];
        for (int o = 0; o < D; ++o) acc = fmaf(Mr[o], vr[o], acc);
        bvo[(size_t)t * D + tid] = acc;
    }
}

// ---------------- merged weight precompute, phase 2 (needs wvo) ----------------
__global__ __launch_bounds__(256) void pre2_kernel(
    const float* __restrict__ wvo,
    const float* __restrict__ W_self1, unsigned short* __restrict__ ws1,
    const float* __restrict__ W_neigh1, unsigned short* __restrict__ wn1,
    const float* __restrict__ b_sage1, const float* __restrict__ bvo, float* __restrict__ b1e)
{
    const int b = blockIdx.x, tid = threadIdx.x;
    if (b < 512) {
        const int t = b >> 8, p = b & 255;
        const float* Xr = wvo + ((size_t)t * D + p) * D;
        const float* Yt = W_self1 + (size_t)t * D * D;
        float acc = 0.f;
        for (int o = 0; o < D; ++o) acc = fmaf(Xr[o], Yt[(size_t)o * D + tid], acc);
        ws1[((size_t)t * D + p) * D + tid] = bf16_rn(acc);
    } else if (b < 1024) {
        const int t = (b - 512) >> 8, p = (b - 512) & 255;
        const float* Xr = wvo + ((size_t)t * D + p) * D;
        const float* Yt = W_neigh1 + (size_t)t * D * D;
        float acc = 0.f;
        for (int o = 0; o < D; ++o) acc = fmaf(Xr[o], Yt[(size_t)o * D + tid], acc);
        wn1[((size_t)t * D + p) * D + tid] = bf16_rn(acc);
    } else {
        const int t = b - 1024;
        const float* Mr = wvo + ((size_t)t * D + tid) * D;
        const float* vr = b_sage1 + (size_t)t * D;
        float acc = bvo[(size_t)t * D + tid];
        for (int o = 0; o < D; ++o) acc = fmaf(Mr[o], vr[o], acc);
        b1e[(size_t)t * D + tid] = acc;
    }
}

// ---------------- B fragments for one 128-wide K-half (L2-resident W) ----------------
__device__ __forceinline__ void load_bfrag(const unsigned short* __restrict__ Wp,
                                           int n0, int wn, int cidx, int rgrp,
                                           int kh, bf16x8 (&bq)[4][4])
{
    #pragma unroll
    for (int n = 0; n < 4; ++n) {
        const int o = n0 + wn + n * 16 + cidx;
        #pragma unroll
        for (int kk = 0; kk < 4; ++kk) {
            frag_cvt c;
            c.u = *(const u32x4*)(Wp + (size_t)o * D + kh * 128 + kk * 32 + rgrp * 8);
            bq[n][kk] = c.h;
        }
    }
}

// ---------------- 128-row A tile -> LDS via global_load_lds (pre-swizzled source) ----------------
__device__ __forceinline__ void gload_tile(const unsigned short* __restrict__ Abase,
                                           int r0, int kt, int tid, char* lbuf)
{
    const int wbase = (tid >> 6) << 10;   // wave-uniform 1KB sub-block
    #pragma unroll
    for (int c = 0; c < 4; ++c) {
        const int p   = c * 4096 + tid * 16;     // physical LDS byte offset
        const int row = p >> 7;                  // 128 B per row (64 bf16)
        const int lwb = p & 127;
        const int lg  = lwb ^ ((row & 7) << 4);  // logical within-row byte
        const unsigned short* g = Abase + (size_t)(r0 + row) * D + kt + (lg >> 1);
        char* l = lbuf + c * 4096 + wbase;       // wave-uniform
        __builtin_amdgcn_global_load_lds(
            (const __attribute__((address_space(1))) unsigned int*)g,
            (__attribute__((address_space(3))) unsigned int*)l, 16, 0, 0);
    }
}

// ======== layer GEMM (r17 exact): Cbf = bf16( A.W1^T + A2[swap].W2^T + bias ) ========
// A via global_load_lds double-buffered; B in registers double-buffered;
// XCD-paired grid (twin n-tiles of an m-panel on one XCD -> A reads L2-hit).
__global__ __launch_bounds__(256, 2) void gemm_bf16_kernel(
    const unsigned short* __restrict__ A, const unsigned short* __restrict__ W1,
    const unsigned short* __restrict__ A2, const unsigned short* __restrict__ W2,
    const float* __restrict__ bias,
    unsigned short* __restrict__ Cbf, int M, int swap2)
{
    const int t   = blockIdx.z;
    const int logical = xcd_logical(blockIdx.x, gridDim.x);
    const int m0  = (logical >> 1) * BM;
    const int n0  = (logical & 1) * BN;
    const int tid = threadIdx.x;
    const int lane = tid & 63;
    const int wid  = tid >> 6;
    const int wm = (wid >> 1) * 64;
    const int wn = (wid & 1) * 64;
    const int rgrp = lane >> 4;
    const int cidx = lane & 15;

    __shared__ __align__(16) unsigned short SH[16384];   // 32 KB: two 16KB A buffers ∪ C half-stage
    char* AsB0 = (char*)SH;
    char* AsB1 = (char*)SH + 16384;

    const int t2 = swap2 ? (1 - t) : t;
    const unsigned short* Aps[2] = { A  + (size_t)t  * M * D, A2 + (size_t)t2 * M * D };
    const unsigned short* Wps[2] = { W1 + (size_t)t  * D * D, W2 + (size_t)t  * D * D };

    f32x4 acc[4][4];
    #pragma unroll
    for (int i = 0; i < 4; ++i)
        #pragma unroll
        for (int j = 0; j < 4; ++j)
            acc[i][j] = (f32x4){0.f, 0.f, 0.f, 0.f};

    bf16x8 bq[2][4][4];
    gload_tile(Aps[0], m0, 0, tid, AsB0);            // tile 0 -> buf0
    load_bfrag(Wps[0], n0, wn, cidx, rgrp, 0, bq[0]);

    #pragma unroll
    for (int idx = 0; idx < 8; ++idx) {
        __syncthreads();
        if (idx < 7)
            gload_tile(Aps[(idx + 1) >> 2], m0, ((idx + 1) & 3) * BK, tid,
                       (idx & 1) ? AsB0 : AsB1);
        if ((idx & 1) == 1 && idx < 7) {
            const int nh = (idx >> 1) + 1;           // next K-half 1..3
            load_bfrag(Wps[nh >> 1], n0, wn, cidx, rgrp, nh & 1, bq[nh & 1]);
        }
        const char* cb = (idx & 1) ? AsB1 : AsB0;
        const int half = idx >> 1;
        #pragma unroll
        for (int ks = 0; ks < 2; ++ks) {
            const int kb = ks * 64 + rgrp * 16;
            bf16x8 af[4];
            #pragma unroll
            for (int m = 0; m < 4; ++m) {
                const int row = wm + m * 16 + cidx;
                const int sw  = (row * 128 + kb) ^ ((row & 7) << 4);
                frag_cvt c; c.u = *(const u32x4*)(cb + sw); af[m] = c.h;
            }
            #pragma unroll
            for (int m = 0; m < 4; ++m)
                #pragma unroll
                for (int n = 0; n < 4; ++n)
                    acc[m][n] = __builtin_amdgcn_mfma_f32_16x16x32_bf16(
                        af[m], bq[half & 1][n][(idx & 1) * 2 + ks], acc[m][n], 0, 0, 0);
        }
        __syncthreads();
    }

    // ---- epilogue: two 64-row halves through LDS, coalesced stores ----
    unsigned short* Ct = Cbf + (size_t)t * M * D;
    #pragma unroll
    for (int h = 0; h < 2; ++h) {
        __syncthreads();
        if ((wid >> 1) == h) {
            #pragma unroll
            for (int n = 0; n < 4; ++n) {
                const int col = wn + n * 16 + cidx;
                const float bc = bias[t * D + n0 + col];
                #pragma unroll
                for (int m = 0; m < 4; ++m) {
                    const int rw = (wm & 63) + m * 16 + rgrp * 4;
                    #pragma unroll
                    for (int i = 0; i < 4; ++i)
                        SH[(rw + i) * 136 + col] = bf16_rn(acc[m][n][i] + bc);
                }
            }
        }
        __syncthreads();
        #pragma unroll
        for (int it = 0; it < 2; ++it) {
            const int g   = tid + it * 256;
            const int row = g >> 3;
            const int cg  = g & 7;
            const int grow = m0 + h * 64 + row;
            if (grow < M) {
                const u32x4 lo = *(const u32x4*)&SH[row * 136 + cg * 16];
                const u32x4 hi = *(const u32x4*)&SH[row * 136 + cg * 16 + 8];
                u32x4* dst = (u32x4*)(Ct + (size_t)grow * D + n0 + cg * 16);
                dst[0] = lo;
                dst[1] = hi;
            }
        }
    }
}

// ======== input GEMM: Cbf = bf16( bf16(X).W^T + bias ) — single-plane ========
// BM=64, 128 threads, (128,2), XCD-paired. X converted to bf16 (RN) during
// staging; lo-plane dropped (downstream is bf16 everywhere + LN renormalizes).
__global__ __launch_bounds__(128, 2) void gemm_in_kernel(
    const float* __restrict__ X, const unsigned short* __restrict__ Wb,
    const float* __restrict__ bias, unsigned short* __restrict__ Cbf, int M)
{
    const int t   = blockIdx.z;
    const int logical = xcd_logical(blockIdx.x, gridDim.x);
    const int m0  = (logical >> 1) * 64;
    const int n0  = (logical & 1) * BN;
    const int tid = threadIdx.x;
    const int lane = tid & 63;
    const int wid  = tid >> 6;
    const int wn = wid * 64;
    const int rgrp = lane >> 4;
    const int cidx = lane & 15;

    __shared__ __align__(16) unsigned short SH[8704];   // 17.4 KB: A(8K) ∪ C stage
    char* AsB = (char*)SH;

    const float* Xp = X + (size_t)t * M * D;
    const unsigned short* Wp = Wb + (size_t)t * D * D;

    f32x4 acc[4][4];
    #pragma unroll
    for (int i = 0; i < 4; ++i)
        #pragma unroll
        for (int j = 0; j < 4; ++j)
            acc[i][j] = (f32x4){0.f, 0.f, 0.f, 0.f};

    bf16x8 bq[2][4][4];
    float4 xr0[4], xr1[4];
    #pragma unroll
    for (int it = 0; it < 4; ++it) {
        const int g = tid + it * 128;     // 0..511
        const int row = g >> 3;           // 0..63
        const int kg = g & 7;
        const int ar = min(m0 + row, M - 1);   // clamp: X is an input buffer
        xr0[it] = *(const float4*)(Xp + (size_t)ar * D + kg * 8);
        xr1[it] = *(const float4*)(Xp + (size_t)ar * D + kg * 8 + 4);
    }
    load_bfrag(Wp, n0, wn, cidx, rgrp, 0, bq[0]);

    #pragma unroll
    for (int kt_i = 0; kt_i < 4; ++kt_i) {
        #pragma unroll
        for (int it = 0; it < 4; ++it) {
            const int g = tid + it * 128;
            const int row = g >> 3;
            const int kg = g & 7;
            unsigned int w[4];
            w[0] = ((unsigned int)bf16_rn(xr0[it].y) << 16) | bf16_rn(xr0[it].x);
            w[1] = ((unsigned int)bf16_rn(xr0[it].w) << 16) | bf16_rn(xr0[it].z);
            w[2] = ((unsigned int)bf16_rn(xr1[it].y) << 16) | bf16_rn(xr1[it].x);
            w[3] = ((unsigned int)bf16_rn(xr1[it].w) << 16) | bf16_rn(xr1[it].z);
            const int sw = ((row * BK + kg * 8) * 2) ^ ((row & 7) << 4);
            *(u32x4*)(AsB + sw) = (u32x4){w[0], w[1], w[2], w[3]};
        }
        __syncthreads();
        if (kt_i < 3) {
            const int kt = (kt_i + 1) * BK;
            #pragma unroll
            for (int it = 0; it < 4; ++it) {
                const int g = tid + it * 128;
                const int row = g >> 3;
                const int kg = g & 7;
                const int ar = min(m0 + row, M - 1);
                xr0[it] = *(const float4*)(Xp + (size_t)ar * D + kt + kg * 8);
                xr1[it] = *(const float4*)(Xp + (size_t)ar * D + kt + kg * 8 + 4);
            }
        }
        if (kt_i == 1) load_bfrag(Wp, n0, wn, cidx, rgrp, 1, bq[1]);  // for kt_i=2,3
        #pragma unroll
        for (int ks = 0; ks < 2; ++ks) {
            const int kb = ks * 64 + rgrp * 16;
            bf16x8 af[4];
            #pragma unroll
            for (int m = 0; m < 4; ++m) {
                const int row = m * 16 + cidx;
                const int sw  = (row * 128 + kb) ^ ((row & 7) << 4);
                frag_cvt c; c.u = *(u32x4*)(AsB + sw); af[m] = c.h;
            }
            #pragma unroll
            for (int m = 0; m < 4; ++m)
                #pragma unroll
                for (int n = 0; n < 4; ++n)
                    acc[m][n] = __builtin_amdgcn_mfma_f32_16x16x32_bf16(
                        af[m], bq[kt_i >> 1][n][(kt_i & 1) * 2 + ks], acc[m][n], 0, 0, 0);
        }
        __syncthreads();
    }

    #pragma unroll
    for (int n = 0; n < 4; ++n) {
        const int col = wn + n * 16 + cidx;
        const float bc = bias[t * D + n0 + col];
        #pragma unroll
        for (int m = 0; m < 4; ++m) {
            const int rowb = m * 16 + rgrp * 4;
            #pragma unroll
            for (int i = 0; i < 4; ++i)
                SH[(rowb + i) * 136 + col] = bf16_rn(acc[m][n][i] + bc);
        }
    }
    __syncthreads();
    unsigned short* Ct = Cbf + (size_t)t * M * D;
    #pragma unroll
    for (int it = 0; it < 4; ++it) {
        const int g   = tid + it * 128;
        const int row = g >> 3;
        const int cg  = g & 7;
        const int grow = m0 + row;
        if (grow < M) {
            const u32x4 lo = *(const u32x4*)&SH[row * 136 + cg * 16];
            const u32x4 hi = *(const u32x4*)&SH[row * 136 + cg * 16 + 8];
            u32x4* dst = (u32x4*)(Ct + (size_t)grow * D + n0 + cg * 16);
            dst[0] = lo;
            dst[1] = hi;
        }
    }
}

// ---------------- LayerNorm, one wave per row; bf16 in/res/out ----------------
__global__ __launch_bounds__(256) void ln_wave_kernel(
    const unsigned short* __restrict__ in_bf, const unsigned short* __restrict__ res_bf,
    const float* __restrict__ g, const float* __restrict__ b,
    unsigned short* __restrict__ out_bf, int N)
{
    const int row  = (blockIdx.x * 256 + threadIdx.x) >> 6;
    const int lane = threadIdx.x & 63;
    if (row >= 2 * N) return;
    const int t = (row >= N) ? 1 : 0;
    const ushort4 iv = *(const ushort4*)(in_bf + (size_t)row * D + lane * 4);
    float4 v = make_float4(bf16_to_f32(iv.x), bf16_to_f32(iv.y),
                           bf16_to_f32(iv.z), bf16_to_f32(iv.w));
    if (res_bf) {
        const ushort4 rv = *(const ushort4*)(res_bf + (size_t)row * D + lane * 4);
        v.x += bf16_to_f32(rv.x); v.y += bf16_to_f32(rv.y);
        v.z += bf16_to_f32(rv.z); v.w += bf16_to_f32(rv.w);
    }
    float s = v.x + v.y + v.z + v.w;
    #pragma unroll
    for (int off = 32; off > 0; off >>= 1) s += __shfl_xor(s, off);
    const float mu = s * (1.0f / 256.0f);
    const float4 dl = make_float4(v.x - mu, v.y - mu, v.z - mu, v.w - mu);
    float q = dl.x * dl.x + dl.y * dl.y + dl.z * dl.z + dl.w * dl.w;
    #pragma unroll
    for (int off = 32; off > 0; off >>= 1) q += __shfl_xor(q, off);
    const float rstd = rsqrtf(q * (1.0f / 256.0f) + 1e-5f);
    const float4 gv = *(const float4*)(g + (size_t)t * D + lane * 4);
    const float4 bv = *(const float4*)(b + (size_t)t * D + lane * 4);
    ushort4 ob;
    ob.x = bf16_rn(dl.x * rstd * gv.x + bv.x);
    ob.y = bf16_rn(dl.y * rstd * gv.y + bv.y);
    ob.z = bf16_rn(dl.z * rstd * gv.z + bv.z);
    ob.w = bf16_rn(dl.w * rstd * gv.w + bv.w);
    *(ushort4*)(out_bf + (size_t)row * D + lane * 4) = ob;
}

// ---------------- CSR build ----------------
__global__ void count_kernel(const int* __restrict__ e_dst, int* __restrict__ cnt,
                             int E2, int N, int E)
{
    const int i = blockIdx.x * 256 + threadIdx.x;
    if (i >= E2) return;
    const int t = i / E;
    atomicAdd(&cnt[(size_t)t * N + e_dst[i]], 1);
}

__global__ __launch_bounds__(256) void scan1_kernel(const int* __restrict__ cnt,
                                                    int* __restrict__ texcl,
                                                    int* __restrict__ bsum, int n, int c)
{
    __shared__ int ts[256];
    const int tid = threadIdx.x;
    const int gt  = blockIdx.x * 256 + tid;
    const int b   = gt * c;
    const int e   = min(b + c, n);
    int s = 0;
    for (int i = b; i < e; ++i) s += cnt[i];
    ts[tid] = s;
    __syncthreads();
    #pragma unroll
    for (int off = 1; off < 256; off <<= 1) {
        const int v = (tid >= off) ? ts[tid - off] : 0;
        __syncthreads();
        ts[tid] += v;
        __syncthreads();
    }
    texcl[gt] = ts[tid] - s;
    if (tid == 255) bsum[blockIdx.x] = ts[255];
}

__global__ __launch_bounds__(64) void scan2_kernel(int* __restrict__ bsum,
                                                   int* __restrict__ bbase,
                                                   int* __restrict__ offs, int n, int nb)
{
    const int lane = threadIdx.x;
    int v = (lane < nb) ? bsum[lane] : 0;
    int s = v;
    #pragma unroll
    for (int off = 1; off < 64; off <<= 1) {
        const int u = __shfl_up(s, off);
        if (lane >= off) s += u;
    }
    if (lane < nb) bbase[lane] = s - v;
    if (lane == 63) offs[n] = s;
}

__global__ __launch_bounds__(256) void scan3_kernel(const int* __restrict__ cnt,
                                                    const int* __restrict__ texcl,
                                                    const int* __restrict__ bbase,
                                                    int* __restrict__ offs, int n, int c)
{
    const int tid = threadIdx.x;
    const int gt  = blockIdx.x * 256 + tid;
    const int b   = gt * c;
    const int e   = min(b + c, n);
    int base = bbase[blockIdx.x] + texcl[gt];
    for (int i = b; i < e; ++i) { offs[i] = base; base += cnt[i]; }
}

__global__ void fill_kernel(const int* __restrict__ e_src, const int* __restrict__ e_dst,
                            const int* __restrict__ offs, int* __restrict__ cur,
                            int* __restrict__ sorted, int E2, int N, int E)
{
    const int i = blockIdx.x * 256 + threadIdx.x;
    if (i >= E2) return;
    const int t = i / E;
    const int idx = t * N + e_dst[i];
    const int pos = offs[idx] + atomicAdd(&cur[idx], 1);
    sorted[pos] = e_src[i];
}

// ---------------- aggregation: one wave per (t,dst), bf16 gather + mean (2-way MLP) ----------------
__global__ __launch_bounds__(256) void agg_kernel(
    const unsigned short* __restrict__ hbf, const int* __restrict__ sorted_src,
    const int* __restrict__ offs, unsigned short* __restrict__ aggbf, int N)
{
    const int gw   = (blockIdx.x * 256 + threadIdx.x) >> 6;
    const int lane = threadIdx.x & 63;
    if (gw >= 2 * N) return;
    const int t = (gw >= N) ? 1 : 0;
    const int beg = offs[gw];
    const int end = offs[gw + 1];
    const unsigned short* hb = hbf + (size_t)t * N * D;
    float4 a0 = make_float4(0.f, 0.f, 0.f, 0.f);
    float4 a1 = make_float4(0.f, 0.f, 0.f, 0.f);
    int e = beg;
    for (; e + 2 <= end; e += 2) {
        const int s0 = sorted_src[e];
        const int s1 = sorted_src[e + 1];
        const ushort4 v0 = *(const ushort4*)(hb + (size_t)s0 * D + lane * 4);
        const ushort4 v1 = *(const ushort4*)(hb + (size_t)s1 * D + lane * 4);
        a0.x += bf16_to_f32(v0.x); a0.y += bf16_to_f32(v0.y);
        a0.z += bf16_to_f32(v0.z); a0.w += bf16_to_f32(v0.w);
        a1.x += bf16_to_f32(v1.x); a1.y += bf16_to_f32(v1.y);
        a1.z += bf16_to_f32(v1.z); a1.w += bf16_to_f32(v1.w);
    }
    if (e < end) {
        const int s0 = sorted_src[e];
        const ushort4 v0 = *(const ushort4*)(hb + (size_t)s0 * D + lane * 4);
        a0.x += bf16_to_f32(v0.x); a0.y += bf16_to_f32(v0.y);
        a0.z += bf16_to_f32(v0.z); a0.w += bf16_to_f32(v0.w);
    }
    const float inv = 1.0f / fmaxf((float)(end - beg), 1.0f);
    ushort4 o;
    o.x = bf16_rn((a0.x + a1.x) * inv); o.y = bf16_rn((a0.y + a1.y) * inv);
    o.z = bf16_rn((a0.z + a1.z) * inv); o.w = bf16_rn((a0.w + a1.w) * inv);
    *(ushort4*)(aggbf + (size_t)gw * D + lane * 4) = o;
}

// ---------------- scores (bf16 h, fp32 accumulate) ----------------
__global__ __launch_bounds__(256) void score_kernel(
    const unsigned short* __restrict__ h,
    const int* __restrict__ pos_src, const int* __restrict__ pos_dst,
    const int* __restrict__ neg_src, const int* __restrict__ neg_dst,
    float* __restrict__ out, int EP, int N)
{
    const int wid  = (blockIdx.x * 256 + threadIdx.x) >> 6;
    const int lane = threadIdx.x & 63;
    if (wid >= 2 * EP) return;
    const int kind = wid / EP;
    const int k    = wid - kind * EP;
    const int s = kind ? neg_src[k] : pos_src[k];
    const int d = kind ? neg_dst[k] : pos_dst[k];
    const ushort4 a = *(const ushort4*)(h + (size_t)s * D + lane * 4);
    const ushort4 b = *(const ushort4*)(h + ((size_t)N + d) * D + lane * 4);
    float v = bf16_to_f32(a.x) * bf16_to_f32(b.x)
            + bf16_to_f32(a.y) * bf16_to_f32(b.y)
            + bf16_to_f32(a.z) * bf16_to_f32(b.z)
            + bf16_to_f32(a.w) * bf16_to_f32(b.w);
    #pragma unroll
    for (int off = 32; off > 0; off >>= 1) v += __shfl_down(v, off);
    if (lane == 0) out[wid] = v;
}

extern "C" void kernel_launch(void* const* d_in, const int* in_sizes, int n_in,
                              void* d_out, int out_size, void* d_ws, size_t ws_size,
                              hipStream_t stream)
{
    const float* x      = (const float*)d_in[0];
    const float* W_in   = (const float*)d_in[1];
    const float* b_in   = (const float*)d_in[2];
    const float* lora_A = (const float*)d_in[3];
    const float* lora_B = (const float*)d_in[4];
    const float* pn_g   = (const float*)d_in[5];
    const float* pn_b   = (const float*)d_in[6];
    const float* W_self = (const float*)d_in[7];
    const float* W_neigh= (const float*)d_in[8];
    const float* b_sage = (const float*)d_in[9];
    const float* ln_g   = (const float*)d_in[10];
    const float* ln_b   = (const float*)d_in[11];
    const float* Wv     = (const float*)d_in[12];
    const float* bvp    = (const float*)d_in[13];
    const float* Wo     = (const float*)d_in[14];
    const float* bo     = (const float*)d_in[15];
    const int* e_src    = (const int*)d_in[16];
    const int* e_dst    = (const int*)d_in[17];
    const int* pos_src  = (const int*)d_in[18];
    const int* pos_dst  = (const int*)d_in[19];
    const int* neg_src  = (const int*)d_in[20];
    const int* neg_dst  = (const int*)d_in[21];

    const int N  = in_sizes[0] / (2 * D);
    const int E  = in_sizes[16] / 2;
    const int EP = in_sizes[18];
    const size_t ND2 = (size_t)2 * N * D;
    const size_t DD2 = (size_t)2 * D * D;
    const int n2 = 2 * N;

    unsigned short* P0 = (unsigned short*)d_ws;
    unsigned short* P1 = P0 + ND2;
    unsigned short* P2 = P1 + ND2;
    unsigned short* T  = P2 + ND2;
    int* cnt    = (int*)(T + ND2);
    int* cur    = cnt + (size_t)n2;          // adjacent to cnt -> single memset
    int* offs   = cur + (size_t)n2;          // n2+1
    int* sorted = offs + (size_t)n2 + 1;
    int* texcl  = sorted + (size_t)2 * E;
    int* bsum   = texcl + SCAN_T;
    int* bbase  = bsum + SCAN_NB;
    float* wvo  = (float*)(bbase + SCAN_NB);
    float* bvo  = wvo + DD2;
    float* b1e  = bvo + 2 * D;
    unsigned short* win_eff = (unsigned short*)(b1e + 2 * D);
    unsigned short* ws0 = win_eff + DD2;
    unsigned short* wn0 = ws0 + DD2;
    unsigned short* ws1 = wn0 + DD2;
    unsigned short* wn1 = ws1 + DD2;

    // ---- weight precompute: 2 merged dispatches ----
    pre1_kernel<<<2050, 256, 0, stream>>>(W_in, lora_A, lora_B, win_eff,
                                          W_self, ws0, W_neigh, wn0,
                                          Wo, Wv, wvo, bvp, bo, bvo);
    pre2_kernel<<<1026, 256, 0, stream>>>(wvo, W_self + DD2, ws1,
                                          W_neigh + DD2, wn1,
                                          b_sage + 2 * D, bvo, b1e);

    // ---- CSR build (edges shared by both layers) ----
    hipMemsetAsync(cnt, 0, (size_t)2 * n2 * sizeof(int), stream);   // cnt + cur
    count_kernel<<<(2 * E + 255) / 256, 256, 0, stream>>>(e_dst, cnt, 2 * E, N, E);
    const int sc = (n2 + SCAN_T - 1) / SCAN_T;
    scan1_kernel<<<SCAN_NB, 256, 0, stream>>>(cnt, texcl, bsum, n2, sc);
    scan2_kernel<<<1, 64, 0, stream>>>(bsum, bbase, offs, n2, SCAN_NB);
    scan3_kernel<<<SCAN_NB, 256, 0, stream>>>(cnt, texcl, bbase, offs, n2, sc);
    fill_kernel<<<(2 * E + 255) / 256, 256, 0, stream>>>(e_src, e_dst, offs, cur, sorted, 2 * E, N, E);

    const dim3 gblk128(128);
    const dim3 gblk(256);
    const int mpan_l = (N + BM - 1) / BM;
    const int mpan_i = (N + 63) / 64;
    const dim3 ggrid(2 * mpan_l, 1, 2);                 // layer GEMM: XCD-paired 1-D
    const dim3 ggrid_in(2 * mpan_i, 1, 2);              // input GEMM: XCD-paired 1-D
    const int ln_grid = (2 * N + 3) / 4;

    // ---- input projection (bf16 single-plane) -> T ; prenorm -> P0 ----
    gemm_in_kernel<<<ggrid_in, gblk128, 0, stream>>>(x, win_eff, b_in, T, N);
    ln_wave_kernel<<<ln_grid, gblk, 0, stream>>>(T, nullptr, pn_g, pn_b, P0, N);

    // ---- layer 0: agg(P0)->P1 ; GEMM -> T ; LN -> P2 ----
    agg_kernel<<<dim3((2 * N + 3) / 4, 1, 1), gblk, 0, stream>>>(P0, sorted, offs, P1, N);
    gemm_bf16_kernel<<<ggrid, gblk, 0, stream>>>(P0, ws0, P1, wn0, b_sage, T, N, 1);
    ln_wave_kernel<<<ln_grid, gblk, 0, stream>>>(T, nullptr, ln_g, ln_b, P2, N);

    // ---- layer 1 (Wv/Wo folded): agg(P2)->P1 ; GEMM -> T ; LN(+res=P2) -> P0 ----
    agg_kernel<<<dim3((2 * N + 3) / 4, 1, 1), gblk, 0, stream>>>(P2, sorted, offs, P1, N);
    gemm_bf16_kernel<<<ggrid, gblk, 0, stream>>>(P2, ws1, P1, wn1, b1e, T, N, 1);
    ln_wave_kernel<<<ln_grid, gblk, 0, stream>>>(T, P2, ln_g + 2 * D, ln_b + 2 * D, P0, N);

    score_kernel<<<(2 * EP + 3) / 4, gblk, 0, stream>>>(P0, pos_src, pos_dst, neg_src, neg_dst,
                                                        (float*)d_out, EP, N);
}

// Round 20
// 466.496 us; speedup vs baseline: 1.1556x; 1.1354x over previous
//
#include <hip/hip_runtime.h>

#define D 256
#define BK 64
#define SCAN_NB 64
#define SCAN_T (SCAN_NB * 256)

typedef __attribute__((ext_vector_type(8))) short bf16x8;
typedef __attribute__((ext_vector_type(4))) float f32x4;
typedef __attribute__((ext_vector_type(4))) unsigned int u32x4;

union frag_cvt { u32x4 u; bf16x8 h; };

__device__ __forceinline__ unsigned short bf16_rn(float f) {
    const unsigned int u = __float_as_uint(f);
    return (unsigned short)((u + 0x7FFFu + ((u >> 16) & 1u)) >> 16);
}
__device__ __forceinline__ float bf16_to_f32(unsigned short s) {
    return __uint_as_float(((unsigned int)s) << 16);
}

// ---------------- merged weight precompute, phase 1 ----------------
__global__ __launch_bounds__(256) void pre1_kernel(
    const float* __restrict__ W_in, const float* __restrict__ lA, const float* __restrict__ lB,
    unsigned short* __restrict__ win_eff,
    const float* __restrict__ W_self, unsigned short* __restrict__ ws0,
    const float* __restrict__ W_neigh, unsigned short* __restrict__ wn0,
    const float* __restrict__ Wo, const float* __restrict__ Wv, float* __restrict__ wvo,
    const float* __restrict__ bvp, const float* __restrict__ bo, float* __restrict__ bvo)
{
    const int b = blockIdx.x, tid = threadIdx.x;
    if (b < 512) {
        const int t = b >> 8, o = b & 255;
        float acc = W_in[((size_t)t * D + o) * D + tid];
        const float* Br = lB + ((size_t)t * D + o) * 16;
        const float* At = lA + (size_t)t * 16 * D;
        #pragma unroll
        for (int r = 0; r < 16; ++r) acc = fmaf(Br[r], At[r * D + tid], acc);
        win_eff[((size_t)t * D + o) * D + tid] = bf16_rn(acc);
    } else if (b < 1024) {
        const int i = (b - 512) * 256 + tid;
        ws0[i] = bf16_rn(W_self[i]);
    } else if (b < 1536) {
        const int i = (b - 1024) * 256 + tid;
        wn0[i] = bf16_rn(W_neigh[i]);
    } else if (b < 2048) {
        const int t = (b - 1536) >> 8, p = (b - 1536) & 255;
        const float* Xr = Wo + ((size_t)t * D + p) * D;
        const float* Yt = Wv + (size_t)t * D * D;
        float acc = 0.f;
        for (int o = 0; o < D; ++o) acc = fmaf(Xr[o], Yt[(size_t)o * D + tid], acc);
        wvo[((size_t)t * D + p) * D + tid] = acc;
    } else {
        const int t = b - 2048;
        const float* Mr = Wo + ((size_t)t * D + tid) * D;
        const float* vr = bvp + (size_t)t * D;
        float acc = bo[(size_t)t * D + tid];
        for (int o = 0; o < D; ++o) acc = fmaf(Mr[o], vr[o], acc);
        bvo[(size_t)t * D + tid] = acc;
    }
}

// ---------------- merged weight precompute, phase 2 (needs wvo) ----------------
__global__ __launch_bounds__(256) void pre2_kernel(
    const float* __restrict__ wvo,
    const float* __restrict__ W_self1, unsigned short* __restrict__ ws1,
    const float* __restrict__ W_neigh1, unsigned short* __restrict__ wn1,
    const float* __restrict__ b_sage1, const float* __restrict__ bvo, float* __restrict__ b1e)
{
    const int b = blockIdx.x, tid = threadIdx.x;
    if (b < 512) {
        const int t = b >> 8, p = b & 255;
        const float* Xr = wvo + ((size_t)t * D + p) * D;
        const float* Yt = W_self1 + (size_t)t * D * D;
        float acc = 0.f;
        for (int o = 0; o < D; ++o) acc = fmaf(Xr[o], Yt[(size_t)o * D + tid], acc);
        ws1[((size_t)t * D + p) * D + tid] = bf16_rn(acc);
    } else if (b < 1024) {
        const int t = (b - 512) >> 8, p = (b - 512) & 255;
        const float* Xr = wvo + ((size_t)t * D + p) * D;
        const float* Yt = W_neigh1 + (size_t)t * D * D;
        float acc = 0.f;
        for (int o = 0; o < D; ++o) acc = fmaf(Xr[o], Yt[(size_t)o * D + tid], acc);
        wn1[((size_t)t * D + p) * D + tid] = bf16_rn(acc);
    } else {
        const int t = b - 1024;
        const float* Mr = wvo + ((size_t)t * D + tid) * D;
        const float* vr = b_sage1 + (size_t)t * D;
        float acc = bvo[(size_t)t * D + tid];
        for (int o = 0; o < D; ++o) acc = fmaf(Mr[o], vr[o], acc);
        b1e[(size_t)t * D + tid] = acc;
    }
}

// ---------------- B fragments for one 128-wide K-half (wave's 64-col slice) ----------------
__device__ __forceinline__ void load_bfrag(const unsigned short* __restrict__ Wp,
                                           int wn, int cidx, int rgrp,
                                           int kh, bf16x8 (&bq)[4][4])
{
    #pragma unroll
    for (int n = 0; n < 4; ++n) {
        const int o = wn + n * 16 + cidx;
        #pragma unroll
        for (int kk = 0; kk < 4; ++kk) {
            frag_cvt c;
            c.u = *(const u32x4*)(Wp + (size_t)o * D + kh * 128 + kk * 32 + rgrp * 8);
            bq[n][kk] = c.h;
        }
    }
}

// ---------------- 64-row A tile -> LDS via global_load_lds (256 thr, pre-swizzled src) ----------------
__device__ __forceinline__ void gload_tile64(const unsigned short* __restrict__ Abase,
                                             int r0, int kt, int tid, char* lbuf)
{
    const int wbase = (tid >> 6) << 10;   // wave-uniform 1KB sub-block
    #pragma unroll
    for (int c = 0; c < 2; ++c) {
        const int p   = c * 4096 + tid * 16;     // physical LDS byte offset (0..8191)
        const int row = p >> 7;                  // 128 B per row (64 bf16)
        const int lwb = p & 127;
        const int lg  = lwb ^ ((row & 7) << 4);  // logical within-row byte
        const unsigned short* g = Abase + (size_t)(r0 + row) * D + kt + (lg >> 1);
        char* l = lbuf + c * 4096 + wbase;       // wave-uniform base; HW adds lane*16
        __builtin_amdgcn_global_load_lds(
            (const __attribute__((address_space(1))) unsigned int*)g,
            (__attribute__((address_space(3))) unsigned int*)l, 16, 0, 0);
    }
}

// ---------------- fused LN epilogue (shared): acc+bias(+res) -> LN -> bf16 out ----------------
__device__ __forceinline__ void ln_epilogue(
    f32x4 (&acc)[4][4], unsigned short* SH,
    const float* __restrict__ bias, const unsigned short* __restrict__ res_bf,
    const float* __restrict__ g, const float* __restrict__ b,
    unsigned short* __restrict__ out_bf,
    int t, int m0, int M, int tid, int wid, int rgrp, int cidx, int wn)
{
    // bias
    #pragma unroll
    for (int n = 0; n < 4; ++n) {
        const float bc = bias[t * D + wn + n * 16 + cidx];
        #pragma unroll
        for (int m = 0; m < 4; ++m)
            #pragma unroll
            for (int i = 0; i < 4; ++i)
                acc[m][n][i] += bc;
    }
    // residual
    if (res_bf) {
        #pragma unroll
        for (int m = 0; m < 4; ++m)
            #pragma unroll
            for (int i = 0; i < 4; ++i) {
                const int row = m * 16 + rgrp * 4 + i;
                const int gr  = min(m0 + row, M - 1);
                const unsigned short* rr = res_bf + ((size_t)t * M + gr) * D + wn + cidx;
                #pragma unroll
                for (int n = 0; n < 4; ++n)
                    acc[m][n][i] += bf16_to_f32(rr[n * 16]);
            }
    }
    // stats scratch beyond the 16KB A-buffer region
    float* red  = (float*)((char*)SH + 16384);   // [64][4]
    float* red2 = red + 256;                      // [64][4]
    float mu[4][4], rs[4][4];
    #pragma unroll
    for (int m = 0; m < 4; ++m)
        #pragma unroll
        for (int i = 0; i < 4; ++i) {
            float s = 0.f;
            #pragma unroll
            for (int n = 0; n < 4; ++n) s += acc[m][n][i];
            s += __shfl_xor(s, 1); s += __shfl_xor(s, 2);
            s += __shfl_xor(s, 4); s += __shfl_xor(s, 8);
            if (cidx == 0) red[(m * 16 + rgrp * 4 + i) * 4 + wid] = s;
        }
    __syncthreads();
    #pragma unroll
    for (int m = 0; m < 4; ++m)
        #pragma unroll
        for (int i = 0; i < 4; ++i) {
            const int row = m * 16 + rgrp * 4 + i;
            mu[m][i] = (red[row * 4] + red[row * 4 + 1] +
                        red[row * 4 + 2] + red[row * 4 + 3]) * (1.0f / 256.0f);
            float q = 0.f;
            #pragma unroll
            for (int n = 0; n < 4; ++n) {
                const float d0 = acc[m][n][i] - mu[m][i];
                q += d0 * d0;
            }
            q += __shfl_xor(q, 1); q += __shfl_xor(q, 2);
            q += __shfl_xor(q, 4); q += __shfl_xor(q, 8);
            if (cidx == 0) red2[row * 4 + wid] = q;
        }
    __syncthreads();
    #pragma unroll
    for (int m = 0; m < 4; ++m)
        #pragma unroll
        for (int i = 0; i < 4; ++i) {
            const int row = m * 16 + rgrp * 4 + i;
            rs[m][i] = rsqrtf((red2[row * 4] + red2[row * 4 + 1] +
                               red2[row * 4 + 2] + red2[row * 4 + 3]) * (1.0f / 256.0f) + 1e-5f);
        }
    __syncthreads();   // all stat reads done; SH free for C stage
    // normalize -> C stage (64 x 264 shorts)
    #pragma unroll
    for (int n = 0; n < 4; ++n) {
        const int col = wn + n * 16 + cidx;
        const float gv = g[t * D + col];
        const float bv = b[t * D + col];
        #pragma unroll
        for (int m = 0; m < 4; ++m)
            #pragma unroll
            for (int i = 0; i < 4; ++i) {
                const int row = m * 16 + rgrp * 4 + i;
                SH[row * 264 + col] = bf16_rn((acc[m][n][i] - mu[m][i]) * rs[m][i] * gv + bv);
            }
    }
    __syncthreads();
    unsigned short* Ct = out_bf + (size_t)t * M * D;
    #pragma unroll
    for (int it = 0; it < 8; ++it) {
        const int gidx = tid + it * 256;     // 0..2047
        const int row  = gidx >> 5;          // 0..63
        const int cg   = gidx & 31;          // 16B chunk
        const int grow = m0 + row;
        if (grow < M) {
            const u32x4 v = *(const u32x4*)&SH[row * 264 + cg * 8];
            *(u32x4*)(Ct + (size_t)grow * D + cg * 8) = v;
        }
    }
}

// ======== fused layer GEMM+LN: out = LN( A.W1^T + A2[swap].W2^T + bias (+res) ) ========
// BM=64 x BN=256(full rows), 256 thr, 4 waves x (64x64). A via global_load_lds
// double-buffered (8KB x2); B in regs double-buffered per K-half.
__global__ __launch_bounds__(256, 2) void gemm_ln_kernel(
    const unsigned short* __restrict__ A, const unsigned short* __restrict__ W1,
    const unsigned short* __restrict__ A2, const unsigned short* __restrict__ W2,
    const float* __restrict__ bias, const unsigned short* __restrict__ res_bf,
    const float* __restrict__ g, const float* __restrict__ b,
    unsigned short* __restrict__ out_bf, int M, int swap2)
{
    const int t   = blockIdx.z;
    const int m0  = blockIdx.x * 64;
    const int tid = threadIdx.x;
    const int lane = tid & 63;
    const int wid  = tid >> 6;          // 0..3
    const int wn = wid * 64;
    const int rgrp = lane >> 4;
    const int cidx = lane & 15;

    __shared__ __align__(16) unsigned short SH[64 * 264];   // 33792 B; A-bufs alias first 16KB
    char* AsB0 = (char*)SH;
    char* AsB1 = (char*)SH + 8192;

    const int t2 = swap2 ? (1 - t) : t;
    const unsigned short* Aps[2] = { A  + (size_t)t  * M * D, A2 + (size_t)t2 * M * D };
    const unsigned short* Wps[2] = { W1 + (size_t)t  * D * D, W2 + (size_t)t  * D * D };

    f32x4 acc[4][4];
    #pragma unroll
    for (int i = 0; i < 4; ++i)
        #pragma unroll
        for (int j = 0; j < 4; ++j)
            acc[i][j] = (f32x4){0.f, 0.f, 0.f, 0.f};

    bf16x8 bq[2][4][4];
    gload_tile64(Aps[0], m0, 0, tid, AsB0);
    load_bfrag(Wps[0], wn, cidx, rgrp, 0, bq[0]);

    #pragma unroll
    for (int idx = 0; idx < 8; ++idx) {
        __syncthreads();
        if (idx < 7)
            gload_tile64(Aps[(idx + 1) >> 2], m0, ((idx + 1) & 3) * BK, tid,
                         (idx & 1) ? AsB0 : AsB1);
        if ((idx & 1) == 1 && idx < 7) {
            const int nh = (idx >> 1) + 1;
            load_bfrag(Wps[nh >> 1], wn, cidx, rgrp, nh & 1, bq[nh & 1]);
        }
        const char* cb = (idx & 1) ? AsB1 : AsB0;
        const int half = idx >> 1;
        #pragma unroll
        for (int ks = 0; ks < 2; ++ks) {
            const int kb = ks * 64 + rgrp * 16;
            bf16x8 af[4];
            #pragma unroll
            for (int m = 0; m < 4; ++m) {
                const int row = m * 16 + cidx;
                const int sw  = (row * 128 + kb) ^ ((row & 7) << 4);
                frag_cvt c; c.u = *(const u32x4*)(cb + sw); af[m] = c.h;
            }
            #pragma unroll
            for (int m = 0; m < 4; ++m)
                #pragma unroll
                for (int n = 0; n < 4; ++n)
                    acc[m][n] = __builtin_amdgcn_mfma_f32_16x16x32_bf16(
                        af[m], bq[half & 1][n][(idx & 1) * 2 + ks], acc[m][n], 0, 0, 0);
        }
        __syncthreads();
    }

    ln_epilogue(acc, SH, bias, res_bf, g, b, out_bf, t, m0, M, tid, wid, rgrp, cidx, wn);
}

// ======== fused input GEMM+LN: out = LN( bf16(X).W^T + bias ) ========
// BM=64 x BN=256, 256 thr; fp32 X converted to bf16 during LDS staging.
__global__ __launch_bounds__(256, 2) void gemm_ln_in_kernel(
    const float* __restrict__ X, const unsigned short* __restrict__ Wb,
    const float* __restrict__ bias,
    const float* __restrict__ g, const float* __restrict__ b,
    unsigned short* __restrict__ out_bf, int M)
{
    const int t   = blockIdx.z;
    const int m0  = blockIdx.x * 64;
    const int tid = threadIdx.x;
    const int lane = tid & 63;
    const int wid  = tid >> 6;
    const int wn = wid * 64;
    const int rgrp = lane >> 4;
    const int cidx = lane & 15;

    __shared__ __align__(16) unsigned short SH[64 * 264];   // A stage aliases first 8KB
    char* AsB = (char*)SH;

    const float* Xp = X + (size_t)t * M * D;
    const unsigned short* Wp = Wb + (size_t)t * D * D;

    f32x4 acc[4][4];
    #pragma unroll
    for (int i = 0; i < 4; ++i)
        #pragma unroll
        for (int j = 0; j < 4; ++j)
            acc[i][j] = (f32x4){0.f, 0.f, 0.f, 0.f};

    bf16x8 bq[2][4][4];
    float4 xr0[2], xr1[2];
    #pragma unroll
    for (int it = 0; it < 2; ++it) {
        const int gi = tid + it * 256;    // 0..511
        const int row = gi >> 3;          // 0..63
        const int kg = gi & 7;
        const int ar = min(m0 + row, M - 1);
        xr0[it] = *(const float4*)(Xp + (size_t)ar * D + kg * 8);
        xr1[it] = *(const float4*)(Xp + (size_t)ar * D + kg * 8 + 4);
    }
    load_bfrag(Wp, wn, cidx, rgrp, 0, bq[0]);

    #pragma unroll
    for (int kt_i = 0; kt_i < 4; ++kt_i) {
        #pragma unroll
        for (int it = 0; it < 2; ++it) {
            const int gi = tid + it * 256;
            const int row = gi >> 3;
            const int kg = gi & 7;
            unsigned int w[4];
            w[0] = ((unsigned int)bf16_rn(xr0[it].y) << 16) | bf16_rn(xr0[it].x);
            w[1] = ((unsigned int)bf16_rn(xr0[it].w) << 16) | bf16_rn(xr0[it].z);
            w[2] = ((unsigned int)bf16_rn(xr1[it].y) << 16) | bf16_rn(xr1[it].x);
            w[3] = ((unsigned int)bf16_rn(xr1[it].w) << 16) | bf16_rn(xr1[it].z);
            const int sw = ((row * BK + kg * 8) * 2) ^ ((row & 7) << 4);
            *(u32x4*)(AsB + sw) = (u32x4){w[0], w[1], w[2], w[3]};
        }
        __syncthreads();
        if (kt_i < 3) {
            const int kt = (kt_i + 1) * BK;
            #pragma unroll
            for (int it = 0; it < 2; ++it) {
                const int gi = tid + it * 256;
                const int row = gi >> 3;
                const int kg = gi & 7;
                const int ar = min(m0 + row, M - 1);
                xr0[it] = *(const float4*)(Xp + (size_t)ar * D + kt + kg * 8);
                xr1[it] = *(const float4*)(Xp + (size_t)ar * D + kt + kg * 8 + 4);
            }
        }
        if (kt_i == 1) load_bfrag(Wp, wn, cidx, rgrp, 1, bq[1]);
        #pragma unroll
        for (int ks = 0; ks < 2; ++ks) {
            const int kb = ks * 64 + rgrp * 16;
            bf16x8 af[4];
            #pragma unroll
            for (int m = 0; m < 4; ++m) {
                const int row = m * 16 + cidx;
                const int sw  = (row * 128 + kb) ^ ((row & 7) << 4);
                frag_cvt c; c.u = *(u32x4*)(AsB + sw); af[m] = c.h;
            }
            #pragma unroll
            for (int m = 0; m < 4; ++m)
                #pragma unroll
                for (int n = 0; n < 4; ++n)
                    acc[m][n] = __builtin_amdgcn_mfma_f32_16x16x32_bf16(
                        af[m], bq[kt_i >> 1][n][(kt_i & 1) * 2 + ks], acc[m][n], 0, 0, 0);
        }
        __syncthreads();
    }

    ln_epilogue(acc, SH, bias, nullptr, g, b, out_bf, t, m0, M, tid, wid, rgrp, cidx, wn);
}

// ---------------- CSR build ----------------
__global__ void count_kernel(const int* __restrict__ e_dst, int* __restrict__ cnt,
                             int E2, int N, int E)
{
    const int i = blockIdx.x * 256 + threadIdx.x;
    if (i >= E2) return;
    const int t = i / E;
    atomicAdd(&cnt[(size_t)t * N + e_dst[i]], 1);
}

__global__ __launch_bounds__(256) void scan1_kernel(const int* __restrict__ cnt,
                                                    int* __restrict__ texcl,
                                                    int* __restrict__ bsum, int n, int c)
{
    __shared__ int ts[256];
    const int tid = threadIdx.x;
    const int gt  = blockIdx.x * 256 + tid;
    const int b   = gt * c;
    const int e   = min(b + c, n);
    int s = 0;
    for (int i = b; i < e; ++i) s += cnt[i];
    ts[tid] = s;
    __syncthreads();
    #pragma unroll
    for (int off = 1; off < 256; off <<= 1) {
        const int v = (tid >= off) ? ts[tid - off] : 0;
        __syncthreads();
        ts[tid] += v;
        __syncthreads();
    }
    texcl[gt] = ts[tid] - s;
    if (tid == 255) bsum[blockIdx.x] = ts[255];
}

__global__ __launch_bounds__(64) void scan2_kernel(int* __restrict__ bsum,
                                                   int* __restrict__ bbase,
                                                   int* __restrict__ offs, int n, int nb)
{
    const int lane = threadIdx.x;
    int v = (lane < nb) ? bsum[lane] : 0;
    int s = v;
    #pragma unroll
    for (int off = 1; off < 64; off <<= 1) {
        const int u = __shfl_up(s, off);
        if (lane >= off) s += u;
    }
    if (lane < nb) bbase[lane] = s - v;
    if (lane == 63) offs[n] = s;
}

__global__ __launch_bounds__(256) void scan3_kernel(const int* __restrict__ cnt,
                                                    const int* __restrict__ texcl,
                                                    const int* __restrict__ bbase,
                                                    int* __restrict__ offs, int n, int c)
{
    const int tid = threadIdx.x;
    const int gt  = blockIdx.x * 256 + tid;
    const int b   = gt * c;
    const int e   = min(b + c, n);
    int base = bbase[blockIdx.x] + texcl[gt];
    for (int i = b; i < e; ++i) { offs[i] = base; base += cnt[i]; }
}

__global__ void fill_kernel(const int* __restrict__ e_src, const int* __restrict__ e_dst,
                            const int* __restrict__ offs, int* __restrict__ cur,
                            int* __restrict__ sorted, int E2, int N, int E)
{
    const int i = blockIdx.x * 256 + threadIdx.x;
    if (i >= E2) return;
    const int t = i / E;
    const int idx = t * N + e_dst[i];
    const int pos = offs[idx] + atomicAdd(&cur[idx], 1);
    sorted[pos] = e_src[i];
}

// ---------------- aggregation: one wave per (t,dst), bf16 gather + mean (2-way MLP) ----------------
__global__ __launch_bounds__(256) void agg_kernel(
    const unsigned short* __restrict__ hbf, const int* __restrict__ sorted_src,
    const int* __restrict__ offs, unsigned short* __restrict__ aggbf, int N)
{
    const int gw   = (blockIdx.x * 256 + threadIdx.x) >> 6;
    const int lane = threadIdx.x & 63;
    if (gw >= 2 * N) return;
    const int t = (gw >= N) ? 1 : 0;
    const int beg = offs[gw];
    const int end = offs[gw + 1];
    const unsigned short* hb = hbf + (size_t)t * N * D;
    float4 a0 = make_float4(0.f, 0.f, 0.f, 0.f);
    float4 a1 = make_float4(0.f, 0.f, 0.f, 0.f);
    int e = beg;
    for (; e + 2 <= end; e += 2) {
        const int s0 = sorted_src[e];
        const int s1 = sorted_src[e + 1];
        const ushort4 v0 = *(const ushort4*)(hb + (size_t)s0 * D + lane * 4);
        const ushort4 v1 = *(const ushort4*)(hb + (size_t)s1 * D + lane * 4);
        a0.x += bf16_to_f32(v0.x); a0.y += bf16_to_f32(v0.y);
        a0.z += bf16_to_f32(v0.z); a0.w += bf16_to_f32(v0.w);
        a1.x += bf16_to_f32(v1.x); a1.y += bf16_to_f32(v1.y);
        a1.z += bf16_to_f32(v1.z); a1.w += bf16_to_f32(v1.w);
    }
    if (e < end) {
        const int s0 = sorted_src[e];
        const ushort4 v0 = *(const ushort4*)(hb + (size_t)s0 * D + lane * 4);
        a0.x += bf16_to_f32(v0.x); a0.y += bf16_to_f32(v0.y);
        a0.z += bf16_to_f32(v0.z); a0.w += bf16_to_f32(v0.w);
    }
    const float inv = 1.0f / fmaxf((float)(end - beg), 1.0f);
    ushort4 o;
    o.x = bf16_rn((a0.x + a1.x) * inv); o.y = bf16_rn((a0.y + a1.y) * inv);
    o.z = bf16_rn((a0.z + a1.z) * inv); o.w = bf16_rn((a0.w + a1.w) * inv);
    *(ushort4*)(aggbf + (size_t)gw * D + lane * 4) = o;
}

// ---------------- scores (bf16 h, fp32 accumulate) ----------------
__global__ __launch_bounds__(256) void score_kernel(
    const unsigned short* __restrict__ h,
    const int* __restrict__ pos_src, const int* __restrict__ pos_dst,
    const int* __restrict__ neg_src, const int* __restrict__ neg_dst,
    float* __restrict__ out, int EP, int N)
{
    const int wid  = (blockIdx.x * 256 + threadIdx.x) >> 6;
    const int lane = threadIdx.x & 63;
    if (wid >= 2 * EP) return;
    const int kind = wid / EP;
    const int k    = wid - kind * EP;
    const int s = kind ? neg_src[k] : pos_src[k];
    const int d = kind ? neg_dst[k] : pos_dst[k];
    const ushort4 a = *(const ushort4*)(h + (size_t)s * D + lane * 4);
    const ushort4 b = *(const ushort4*)(h + ((size_t)N + d) * D + lane * 4);
    float v = bf16_to_f32(a.x) * bf16_to_f32(b.x)
            + bf16_to_f32(a.y) * bf16_to_f32(b.y)
            + bf16_to_f32(a.z) * bf16_to_f32(b.z)
            + bf16_to_f32(a.w) * bf16_to_f32(b.w);
    #pragma unroll
    for (int off = 32; off > 0; off >>= 1) v += __shfl_down(v, off);
    if (lane == 0) out[wid] = v;
}

extern "C" void kernel_launch(void* const* d_in, const int* in_sizes, int n_in,
                              void* d_out, int out_size, void* d_ws, size_t ws_size,
                              hipStream_t stream)
{
    const float* x      = (const float*)d_in[0];
    const float* W_in   = (const float*)d_in[1];
    const float* b_in   = (const float*)d_in[2];
    const float* lora_A = (const float*)d_in[3];
    const float* lora_B = (const float*)d_in[4];
    const float* pn_g   = (const float*)d_in[5];
    const float* pn_b   = (const float*)d_in[6];
    const float* W_self = (const float*)d_in[7];
    const float* W_neigh= (const float*)d_in[8];
    const float* b_sage = (const float*)d_in[9];
    const float* ln_g   = (const float*)d_in[10];
    const float* ln_b   = (const float*)d_in[11];
    const float* Wv     = (const float*)d_in[12];
    const float* bvp    = (const float*)d_in[13];
    const float* Wo     = (const float*)d_in[14];
    const float* bo     = (const float*)d_in[15];
    const int* e_src    = (const int*)d_in[16];
    const int* e_dst    = (const int*)d_in[17];
    const int* pos_src  = (const int*)d_in[18];
    const int* pos_dst  = (const int*)d_in[19];
    const int* neg_src  = (const int*)d_in[20];
    const int* neg_dst  = (const int*)d_in[21];

    const int N  = in_sizes[0] / (2 * D);
    const int E  = in_sizes[16] / 2;
    const int EP = in_sizes[18];
    const size_t ND2 = (size_t)2 * N * D;
    const size_t DD2 = (size_t)2 * D * D;
    const int n2 = 2 * N;

    unsigned short* P0 = (unsigned short*)d_ws;
    unsigned short* P1 = P0 + ND2;
    unsigned short* P2 = P1 + ND2;
    unsigned short* T  = P2 + ND2;              // spare (tail-read slack for GEMM A)
    int* cnt    = (int*)(T + ND2);
    int* cur    = cnt + (size_t)n2;
    int* offs   = cur + (size_t)n2;             // n2+1
    int* sorted = offs + (size_t)n2 + 1;
    int* texcl  = sorted + (size_t)2 * E;
    int* bsum   = texcl + SCAN_T;
    int* bbase  = bsum + SCAN_NB;
    float* wvo  = (float*)(bbase + SCAN_NB);
    float* bvo  = wvo + DD2;
    float* b1e  = bvo + 2 * D;
    unsigned short* win_eff = (unsigned short*)(b1e + 2 * D);
    unsigned short* ws0 = win_eff + DD2;
    unsigned short* wn0 = ws0 + DD2;
    unsigned short* ws1 = wn0 + DD2;
    unsigned short* wn1 = ws1 + DD2;

    // ---- weight precompute: 2 merged dispatches ----
    pre1_kernel<<<2050, 256, 0, stream>>>(W_in, lora_A, lora_B, win_eff,
                                          W_self, ws0, W_neigh, wn0,
                                          Wo, Wv, wvo, bvp, bo, bvo);
    pre2_kernel<<<1026, 256, 0, stream>>>(wvo, W_self + DD2, ws1,
                                          W_neigh + DD2, wn1,
                                          b_sage + 2 * D, bvo, b1e);

    // ---- CSR build (edges shared by both layers) ----
    hipMemsetAsync(cnt, 0, (size_t)2 * n2 * sizeof(int), stream);
    count_kernel<<<(2 * E + 255) / 256, 256, 0, stream>>>(e_dst, cnt, 2 * E, N, E);
    const int sc = (n2 + SCAN_T - 1) / SCAN_T;
    scan1_kernel<<<SCAN_NB, 256, 0, stream>>>(cnt, texcl, bsum, n2, sc);
    scan2_kernel<<<1, 64, 0, stream>>>(bsum, bbase, offs, n2, SCAN_NB);
    scan3_kernel<<<SCAN_NB, 256, 0, stream>>>(cnt, texcl, bbase, offs, n2, sc);
    fill_kernel<<<(2 * E + 255) / 256, 256, 0, stream>>>(e_src, e_dst, offs, cur, sorted, 2 * E, N, E);

    const dim3 gblk(256);
    const int mpan = (N + 63) / 64;             // 782
    const dim3 fgrid(mpan, 1, 2);

    // ---- input projection + prenorm (fused) -> P0 ----
    gemm_ln_in_kernel<<<fgrid, gblk, 0, stream>>>(x, win_eff, b_in, pn_g, pn_b, P0, N);

    // ---- layer 0: agg(P0)->P1 ; fused GEMM+LN -> P2 ----
    agg_kernel<<<dim3((2 * N + 3) / 4, 1, 1), gblk, 0, stream>>>(P0, sorted, offs, P1, N);
    gemm_ln_kernel<<<fgrid, gblk, 0, stream>>>(P0, ws0, P1, wn0, b_sage, nullptr,
                                               ln_g, ln_b, P2, N, 1);

    // ---- layer 1 (Wv/Wo folded): agg(P2)->P1 ; fused GEMM+LN(+res=P2) -> P0 ----
    agg_kernel<<<dim3((2 * N + 3) / 4, 1, 1), gblk, 0, stream>>>(P2, sorted, offs, P1, N);
    gemm_ln_kernel<<<fgrid, gblk, 0, stream>>>(P2, ws1, P1, wn1, b1e, P2,
                                               ln_g + 2 * D, ln_b + 2 * D, P0, N, 1);

    score_kernel<<<(2 * EP + 3) / 4, gblk, 0, stream>>>(P0, pos_src, pos_dst, neg_src, neg_dst,
                                                        (float*)d_out, EP, N);
}

// Round 21
// 431.930 us; speedup vs baseline: 1.2481x; 1.0800x over previous
//
#include <hip/hip_runtime.h>

#define D 256
#define BK 64
#define SCAN_NB 64
#define SCAN_T (SCAN_NB * 256)

typedef __attribute__((ext_vector_type(8))) short bf16x8;
typedef __attribute__((ext_vector_type(4))) float f32x4;
typedef __attribute__((ext_vector_type(4))) unsigned int u32x4;

union frag_cvt { u32x4 u; bf16x8 h; };

__device__ __forceinline__ unsigned short bf16_rn(float f) {
    const unsigned int u = __float_as_uint(f);
    return (unsigned short)((u + 0x7FFFu + ((u >> 16) & 1u)) >> 16);
}
__device__ __forceinline__ float bf16_to_f32(unsigned short s) {
    return __uint_as_float(((unsigned int)s) << 16);
}

// ---------------- merged weight precompute, phase 1 ----------------
__global__ __launch_bounds__(256) void pre1_kernel(
    const float* __restrict__ W_in, const float* __restrict__ lA, const float* __restrict__ lB,
    unsigned short* __restrict__ win_eff,
    const float* __restrict__ W_self, unsigned short* __restrict__ ws0,
    const float* __restrict__ W_neigh, unsigned short* __restrict__ wn0,
    const float* __restrict__ Wo, const float* __restrict__ Wv, float* __restrict__ wvo,
    const float* __restrict__ bvp, const float* __restrict__ bo, float* __restrict__ bvo)
{
    const int b = blockIdx.x, tid = threadIdx.x;
    if (b < 512) {
        const int t = b >> 8, o = b & 255;
        float acc = W_in[((size_t)t * D + o) * D + tid];
        const float* Br = lB + ((size_t)t * D + o) * 16;
        const float* At = lA + (size_t)t * 16 * D;
        #pragma unroll
        for (int r = 0; r < 16; ++r) acc = fmaf(Br[r], At[r * D + tid], acc);
        win_eff[((size_t)t * D + o) * D + tid] = bf16_rn(acc);
    } else if (b < 1024) {
        const int i = (b - 512) * 256 + tid;
        ws0[i] = bf16_rn(W_self[i]);
    } else if (b < 1536) {
        const int i = (b - 1024) * 256 + tid;
        wn0[i] = bf16_rn(W_neigh[i]);
    } else if (b < 2048) {
        const int t = (b - 1536) >> 8, p = (b - 1536) & 255;
        const float* Xr = Wo + ((size_t)t * D + p) * D;
        const float* Yt = Wv + (size_t)t * D * D;
        float acc = 0.f;
        for (int o = 0; o < D; ++o) acc = fmaf(Xr[o], Yt[(size_t)o * D + tid], acc);
        wvo[((size_t)t * D + p) * D + tid] = acc;
    } else {
        const int t = b - 2048;
        const float* Mr = Wo + ((size_t)t * D + tid) * D;
        const float* vr = bvp + (size_t)t * D;
        float acc = bo[(size_t)t * D + tid];
        for (int o = 0; o < D; ++o) acc = fmaf(Mr[o], vr[o], acc);
        bvo[(size_t)t * D + tid] = acc;
    }
}

// ---------------- merged weight precompute, phase 2 (needs wvo) ----------------
__global__ __launch_bounds__(256) void pre2_kernel(
    const float* __restrict__ wvo,
    const float* __restrict__ W_self1, unsigned short* __restrict__ ws1,
    const float* __restrict__ W_neigh1, unsigned short* __restrict__ wn1,
    const float* __restrict__ b_sage1, const float* __restrict__ bvo, float* __restrict__ b1e)
{
    const int b = blockIdx.x, tid = threadIdx.x;
    if (b < 512) {
        const int t = b >> 8, p = b & 255;
        const float* Xr = wvo + ((size_t)t * D + p) * D;
        const float* Yt = W_self1 + (size_t)t * D * D;
        float acc = 0.f;
        for (int o = 0; o < D; ++o) acc = fmaf(Xr[o], Yt[(size_t)o * D + tid], acc);
        ws1[((size_t)t * D + p) * D + tid] = bf16_rn(acc);
    } else if (b < 1024) {
        const int t = (b - 512) >> 8, p = (b - 512) & 255;
        const float* Xr = wvo + ((size_t)t * D + p) * D;
        const float* Yt = W_neigh1 + (size_t)t * D * D;
        float acc = 0.f;
        for (int o = 0; o < D; ++o) acc = fmaf(Xr[o], Yt[(size_t)o * D + tid], acc);
        wn1[((size_t)t * D + p) * D + tid] = bf16_rn(acc);
    } else {
        const int t = b - 1024;
        const float* Mr = wvo + ((size_t)t * D + tid) * D;
        const float* vr = b_sage1 + (size_t)t * D;
        float acc = bvo[(size_t)t * D + tid];
        for (int o = 0; o < D; ++o) acc = fmaf(Mr[o], vr[o], acc);
        b1e[(size_t)t * D + tid] = acc;
    }
}

// ---------------- B fragments for one 128-wide K-half (wave's 64-col slice) ----------------
__device__ __forceinline__ void load_bfrag(const unsigned short* __restrict__ Wp,
                                           int wn, int cidx, int rgrp,
                                           int kh, bf16x8 (&bq)[4][4])
{
    #pragma unroll
    for (int n = 0; n < 4; ++n) {
        const int o = wn + n * 16 + cidx;
        #pragma unroll
        for (int kk = 0; kk < 4; ++kk) {
            frag_cvt c;
            c.u = *(const u32x4*)(Wp + (size_t)o * D + kh * 128 + kk * 32 + rgrp * 8);
            bq[n][kk] = c.h;
        }
    }
}

// ---------------- 64-row A tile -> LDS via global_load_lds (256 thr, pre-swizzled src) ----------------
__device__ __forceinline__ void gload_tile64(const unsigned short* __restrict__ Abase,
                                             int r0, int kt, int tid, char* lbuf)
{
    const int wbase = (tid >> 6) << 10;   // wave-uniform 1KB sub-block
    #pragma unroll
    for (int c = 0; c < 2; ++c) {
        const int p   = c * 4096 + tid * 16;     // physical LDS byte offset (0..8191)
        const int row = p >> 7;                  // 128 B per row (64 bf16)
        const int lwb = p & 127;
        const int lg  = lwb ^ ((row & 7) << 4);  // logical within-row byte
        const unsigned short* g = Abase + (size_t)(r0 + row) * D + kt + (lg >> 1);
        char* l = lbuf + c * 4096 + wbase;       // wave-uniform base; HW adds lane*16
        __builtin_amdgcn_global_load_lds(
            (const __attribute__((address_space(1))) unsigned int*)g,
            (__attribute__((address_space(3))) unsigned int*)l, 16, 0, 0);
    }
}

// ---------------- fused LN epilogue: acc+bias(+res) -> LN (single-pass stats) -> bf16 out ----------------
__device__ __forceinline__ void ln_epilogue(
    f32x4 (&acc)[4][4], unsigned short* SH,
    const float* __restrict__ bias, const unsigned short* __restrict__ res_bf,
    const float* __restrict__ g, const float* __restrict__ b,
    unsigned short* __restrict__ out_bf,
    int t, int m0, int M, int tid, int wid, int rgrp, int cidx, int wn)
{
    // bias
    #pragma unroll
    for (int n = 0; n < 4; ++n) {
        const float bc = bias[t * D + wn + n * 16 + cidx];
        #pragma unroll
        for (int m = 0; m < 4; ++m)
            #pragma unroll
            for (int i = 0; i < 4; ++i)
                acc[m][n][i] += bc;
    }
    // residual
    if (res_bf) {
        #pragma unroll
        for (int m = 0; m < 4; ++m)
            #pragma unroll
            for (int i = 0; i < 4; ++i) {
                const int row = m * 16 + rgrp * 4 + i;
                const int gr  = min(m0 + row, M - 1);
                const unsigned short* rr = res_bf + ((size_t)t * M + gr) * D + wn + cidx;
                #pragma unroll
                for (int n = 0; n < 4; ++n)
                    acc[m][n][i] += bf16_to_f32(rr[n * 16]);
            }
    }
    // single-pass stats: s = Σx, q = Σx² per row (E[x²]-µ² variance)
    float* red  = (float*)((char*)SH + 16384);   // [64][4] sums
    float* red2 = red + 256;                      // [64][4] sqsums
    float mu[4][4], rs[4][4];
    #pragma unroll
    for (int m = 0; m < 4; ++m)
        #pragma unroll
        for (int i = 0; i < 4; ++i) {
            float s = 0.f, q = 0.f;
            #pragma unroll
            for (int n = 0; n < 4; ++n) {
                const float v = acc[m][n][i];
                s += v; q += v * v;
            }
            s += __shfl_xor(s, 1); q += __shfl_xor(q, 1);
            s += __shfl_xor(s, 2); q += __shfl_xor(q, 2);
            s += __shfl_xor(s, 4); q += __shfl_xor(q, 4);
            s += __shfl_xor(s, 8); q += __shfl_xor(q, 8);
            if (cidx == 0) {
                const int row = m * 16 + rgrp * 4 + i;
                red[row * 4 + wid]  = s;
                red2[row * 4 + wid] = q;
            }
        }
    __syncthreads();
    #pragma unroll
    for (int m = 0; m < 4; ++m)
        #pragma unroll
        for (int i = 0; i < 4; ++i) {
            const int row = m * 16 + rgrp * 4 + i;
            const float S = red[row * 4] + red[row * 4 + 1] + red[row * 4 + 2] + red[row * 4 + 3];
            const float Q = red2[row * 4] + red2[row * 4 + 1] + red2[row * 4 + 2] + red2[row * 4 + 3];
            const float m_ = S * (1.0f / 256.0f);
            float var = Q * (1.0f / 256.0f) - m_ * m_;
            var = fmaxf(var, 0.f);
            mu[m][i] = m_;
            rs[m][i] = rsqrtf(var + 1e-5f);
        }
    __syncthreads();   // stat reads done; SH free for C stage
    // normalize -> C stage (64 x 264 shorts)
    #pragma unroll
    for (int n = 0; n < 4; ++n) {
        const int col = wn + n * 16 + cidx;
        const float gv = g[t * D + col];
        const float bv = b[t * D + col];
        #pragma unroll
        for (int m = 0; m < 4; ++m)
            #pragma unroll
            for (int i = 0; i < 4; ++i) {
                const int row = m * 16 + rgrp * 4 + i;
                SH[row * 264 + col] = bf16_rn((acc[m][n][i] - mu[m][i]) * rs[m][i] * gv + bv);
            }
    }
    __syncthreads();
    unsigned short* Ct = out_bf + (size_t)t * M * D;
    #pragma unroll
    for (int it = 0; it < 8; ++it) {
        const int gidx = tid + it * 256;     // 0..2047
        const int row  = gidx >> 5;          // 0..63
        const int cg   = gidx & 31;          // 16B chunk
        const int grow = m0 + row;
        if (grow < M) {
            const u32x4 v = *(const u32x4*)&SH[row * 264 + cg * 8];
            *(u32x4*)(Ct + (size_t)grow * D + cg * 8) = v;
        }
    }
}

// ======== fused layer GEMM+LN: out = LN( A.W1^T + A2[swap].W2^T + bias (+res) ) ========
__global__ __launch_bounds__(256, 2) void gemm_ln_kernel(
    const unsigned short* __restrict__ A, const unsigned short* __restrict__ W1,
    const unsigned short* __restrict__ A2, const unsigned short* __restrict__ W2,
    const float* __restrict__ bias, const unsigned short* __restrict__ res_bf,
    const float* __restrict__ g, const float* __restrict__ b,
    unsigned short* __restrict__ out_bf, int M, int swap2)
{
    const int t   = blockIdx.z;
    const int m0  = blockIdx.x * 64;
    const int tid = threadIdx.x;
    const int lane = tid & 63;
    const int wid  = tid >> 6;          // 0..3
    const int wn = wid * 64;
    const int rgrp = lane >> 4;
    const int cidx = lane & 15;

    __shared__ __align__(16) unsigned short SH[64 * 264];   // 33792 B; A-bufs alias first 16KB
    char* AsB0 = (char*)SH;
    char* AsB1 = (char*)SH + 8192;

    const int t2 = swap2 ? (1 - t) : t;
    const unsigned short* Aps[2] = { A  + (size_t)t  * M * D, A2 + (size_t)t2 * M * D };
    const unsigned short* Wps[2] = { W1 + (size_t)t  * D * D, W2 + (size_t)t  * D * D };

    f32x4 acc[4][4];
    #pragma unroll
    for (int i = 0; i < 4; ++i)
        #pragma unroll
        for (int j = 0; j < 4; ++j)
            acc[i][j] = (f32x4){0.f, 0.f, 0.f, 0.f};

    bf16x8 bq[2][4][4];
    gload_tile64(Aps[0], m0, 0, tid, AsB0);
    load_bfrag(Wps[0], wn, cidx, rgrp, 0, bq[0]);

    #pragma unroll
    for (int idx = 0; idx < 8; ++idx) {
        __syncthreads();
        if (idx < 7)
            gload_tile64(Aps[(idx + 1) >> 2], m0, ((idx + 1) & 3) * BK, tid,
                         (idx & 1) ? AsB0 : AsB1);
        if ((idx & 1) == 1 && idx < 7) {
            const int nh = (idx >> 1) + 1;
            load_bfrag(Wps[nh >> 1], wn, cidx, rgrp, nh & 1, bq[nh & 1]);
        }
        const char* cb = (idx & 1) ? AsB1 : AsB0;
        const int half = idx >> 1;
        #pragma unroll
        for (int ks = 0; ks < 2; ++ks) {
            const int kb = ks * 64 + rgrp * 16;
            bf16x8 af[4];
            #pragma unroll
            for (int m = 0; m < 4; ++m) {
                const int row = m * 16 + cidx;
                const int sw  = (row * 128 + kb) ^ ((row & 7) << 4);
                frag_cvt c; c.u = *(const u32x4*)(cb + sw); af[m] = c.h;
            }
            #pragma unroll
            for (int m = 0; m < 4; ++m)
                #pragma unroll
                for (int n = 0; n < 4; ++n)
                    acc[m][n] = __builtin_amdgcn_mfma_f32_16x16x32_bf16(
                        af[m], bq[half & 1][n][(idx & 1) * 2 + ks], acc[m][n], 0, 0, 0);
        }
        __syncthreads();
    }

    ln_epilogue(acc, SH, bias, res_bf, g, b, out_bf, t, m0, M, tid, wid, rgrp, cidx, wn);
}

// ======== fused input GEMM+LN: out = LN( bf16(X).W^T + bias ) ========
__global__ __launch_bounds__(256, 2) void gemm_ln_in_kernel(
    const float* __restrict__ X, const unsigned short* __restrict__ Wb,
    const float* __restrict__ bias,
    const float* __restrict__ g, const float* __restrict__ b,
    unsigned short* __restrict__ out_bf, int M)
{
    const int t   = blockIdx.z;
    const int m0  = blockIdx.x * 64;
    const int tid = threadIdx.x;
    const int lane = tid & 63;
    const int wid  = tid >> 6;
    const int wn = wid * 64;
    const int rgrp = lane >> 4;
    const int cidx = lane & 15;

    __shared__ __align__(16) unsigned short SH[64 * 264];   // A stage aliases first 8KB
    char* AsB = (char*)SH;

    const float* Xp = X + (size_t)t * M * D;
    const unsigned short* Wp = Wb + (size_t)t * D * D;

    f32x4 acc[4][4];
    #pragma unroll
    for (int i = 0; i < 4; ++i)
        #pragma unroll
        for (int j = 0; j < 4; ++j)
            acc[i][j] = (f32x4){0.f, 0.f, 0.f, 0.f};

    bf16x8 bq[2][4][4];
    float4 xr0[2], xr1[2];
    #pragma unroll
    for (int it = 0; it < 2; ++it) {
        const int gi = tid + it * 256;    // 0..511
        const int row = gi >> 3;          // 0..63
        const int kg = gi & 7;
        const int ar = min(m0 + row, M - 1);
        xr0[it] = *(const float4*)(Xp + (size_t)ar * D + kg * 8);
        xr1[it] = *(const float4*)(Xp + (size_t)ar * D + kg * 8 + 4);
    }
    load_bfrag(Wp, wn, cidx, rgrp, 0, bq[0]);

    #pragma unroll
    for (int kt_i = 0; kt_i < 4; ++kt_i) {
        #pragma unroll
        for (int it = 0; it < 2; ++it) {
            const int gi = tid + it * 256;
            const int row = gi >> 3;
            const int kg = gi & 7;
            unsigned int w[4];
            w[0] = ((unsigned int)bf16_rn(xr0[it].y) << 16) | bf16_rn(xr0[it].x);
            w[1] = ((unsigned int)bf16_rn(xr0[it].w) << 16) | bf16_rn(xr0[it].z);
            w[2] = ((unsigned int)bf16_rn(xr1[it].y) << 16) | bf16_rn(xr1[it].x);
            w[3] = ((unsigned int)bf16_rn(xr1[it].w) << 16) | bf16_rn(xr1[it].z);
            const int sw = ((row * BK + kg * 8) * 2) ^ ((row & 7) << 4);
            *(u32x4*)(AsB + sw) = (u32x4){w[0], w[1], w[2], w[3]};
        }
        __syncthreads();
        if (kt_i < 3) {
            const int kt = (kt_i + 1) * BK;
            #pragma unroll
            for (int it = 0; it < 2; ++it) {
                const int gi = tid + it * 256;
                const int row = gi >> 3;
                const int kg = gi & 7;
                const int ar = min(m0 + row, M - 1);
                xr0[it] = *(const float4*)(Xp + (size_t)ar * D + kt + kg * 8);
                xr1[it] = *(const float4*)(Xp + (size_t)ar * D + kt + kg * 8 + 4);
            }
        }
        if (kt_i == 1) load_bfrag(Wp, wn, cidx, rgrp, 1, bq[1]);
        #pragma unroll
        for (int ks = 0; ks < 2; ++ks) {
            const int kb = ks * 64 + rgrp * 16;
            bf16x8 af[4];
            #pragma unroll
            for (int m = 0; m < 4; ++m) {
                const int row = m * 16 + cidx;
                const int sw  = (row * 128 + kb) ^ ((row & 7) << 4);
                frag_cvt c; c.u = *(u32x4*)(AsB + sw); af[m] = c.h;
            }
            #pragma unroll
            for (int m = 0; m < 4; ++m)
                #pragma unroll
                for (int n = 0; n < 4; ++n)
                    acc[m][n] = __builtin_amdgcn_mfma_f32_16x16x32_bf16(
                        af[m], bq[kt_i >> 1][n][(kt_i & 1) * 2 + ks], acc[m][n], 0, 0, 0);
        }
        __syncthreads();
    }

    ln_epilogue(acc, SH, bias, nullptr, g, b, out_bf, t, m0, M, tid, wid, rgrp, cidx, wn);
}

// ---------------- CSR build ----------------
__global__ void count_kernel(const int* __restrict__ e_dst, int* __restrict__ cnt,
                             int E2, int N, int E)
{
    const int i = blockIdx.x * 256 + threadIdx.x;
    if (i >= E2) return;
    const int t = i / E;
    atomicAdd(&cnt[(size_t)t * N + e_dst[i]], 1);
}

__global__ __launch_bounds__(256) void scan1_kernel(const int* __restrict__ cnt,
                                                    int* __restrict__ texcl,
                                                    int* __restrict__ bsum, int n, int c)
{
    __shared__ int ts[256];
    const int tid = threadIdx.x;
    const int gt  = blockIdx.x * 256 + tid;
    const int b   = gt * c;
    const int e   = min(b + c, n);
    int s = 0;
    for (int i = b; i < e; ++i) s += cnt[i];
    ts[tid] = s;
    __syncthreads();
    #pragma unroll
    for (int off = 1; off < 256; off <<= 1) {
        const int v = (tid >= off) ? ts[tid - off] : 0;
        __syncthreads();
        ts[tid] += v;
        __syncthreads();
    }
    texcl[gt] = ts[tid] - s;
    if (tid == 255) bsum[blockIdx.x] = ts[255];
}

__global__ __launch_bounds__(64) void scan2_kernel(int* __restrict__ bsum,
                                                   int* __restrict__ bbase,
                                                   int* __restrict__ offs, int n, int nb)
{
    const int lane = threadIdx.x;
    int v = (lane < nb) ? bsum[lane] : 0;
    int s = v;
    #pragma unroll
    for (int off = 1; off < 64; off <<= 1) {
        const int u = __shfl_up(s, off);
        if (lane >= off) s += u;
    }
    if (lane < nb) bbase[lane] = s - v;
    if (lane == 63) offs[n] = s;
}

__global__ __launch_bounds__(256) void scan3_kernel(const int* __restrict__ cnt,
                                                    const int* __restrict__ texcl,
                                                    const int* __restrict__ bbase,
                                                    int* __restrict__ offs, int n, int c)
{
    const int tid = threadIdx.x;
    const int gt  = blockIdx.x * 256 + tid;
    const int b   = gt * c;
    const int e   = min(b + c, n);
    int base = bbase[blockIdx.x] + texcl[gt];
    for (int i = b; i < e; ++i) { offs[i] = base; base += cnt[i]; }
}

__global__ void fill_kernel(const int* __restrict__ e_src, const int* __restrict__ e_dst,
                            const int* __restrict__ offs, int* __restrict__ cur,
                            int* __restrict__ sorted, int E2, int N, int E)
{
    const int i = blockIdx.x * 256 + threadIdx.x;
    if (i >= E2) return;
    const int t = i / E;
    const int idx = t * N + e_dst[i];
    const int pos = offs[idx] + atomicAdd(&cur[idx], 1);
    sorted[pos] = e_src[i];
}

// ---------------- aggregation: one wave per (t,dst), bf16 gather + mean (4-way MLP) ----------------
__global__ __launch_bounds__(256) void agg_kernel(
    const unsigned short* __restrict__ hbf, const int* __restrict__ sorted_src,
    const int* __restrict__ offs, unsigned short* __restrict__ aggbf, int N)
{
    const int gw   = (blockIdx.x * 256 + threadIdx.x) >> 6;
    const int lane = threadIdx.x & 63;
    if (gw >= 2 * N) return;
    const int t = (gw >= N) ? 1 : 0;
    const int beg = offs[gw];
    const int end = offs[gw + 1];
    const unsigned short* hb = hbf + (size_t)t * N * D;
    float4 a0 = make_float4(0.f, 0.f, 0.f, 0.f);
    float4 a1 = make_float4(0.f, 0.f, 0.f, 0.f);
    float4 a2 = make_float4(0.f, 0.f, 0.f, 0.f);
    float4 a3 = make_float4(0.f, 0.f, 0.f, 0.f);
    int e = beg;
    for (; e + 4 <= end; e += 4) {
        const int s0 = sorted_src[e];
        const int s1 = sorted_src[e + 1];
        const int s2 = sorted_src[e + 2];
        const int s3 = sorted_src[e + 3];
        const ushort4 v0 = *(const ushort4*)(hb + (size_t)s0 * D + lane * 4);
        const ushort4 v1 = *(const ushort4*)(hb + (size_t)s1 * D + lane * 4);
        const ushort4 v2 = *(const ushort4*)(hb + (size_t)s2 * D + lane * 4);
        const ushort4 v3 = *(const ushort4*)(hb + (size_t)s3 * D + lane * 4);
        a0.x += bf16_to_f32(v0.x); a0.y += bf16_to_f32(v0.y);
        a0.z += bf16_to_f32(v0.z); a0.w += bf16_to_f32(v0.w);
        a1.x += bf16_to_f32(v1.x); a1.y += bf16_to_f32(v1.y);
        a1.z += bf16_to_f32(v1.z); a1.w += bf16_to_f32(v1.w);
        a2.x += bf16_to_f32(v2.x); a2.y += bf16_to_f32(v2.y);
        a2.z += bf16_to_f32(v2.z); a2.w += bf16_to_f32(v2.w);
        a3.x += bf16_to_f32(v3.x); a3.y += bf16_to_f32(v3.y);
        a3.z += bf16_to_f32(v3.z); a3.w += bf16_to_f32(v3.w);
    }
    for (; e < end; ++e) {
        const int s0 = sorted_src[e];
        const ushort4 v0 = *(const ushort4*)(hb + (size_t)s0 * D + lane * 4);
        a0.x += bf16_to_f32(v0.x); a0.y += bf16_to_f32(v0.y);
        a0.z += bf16_to_f32(v0.z); a0.w += bf16_to_f32(v0.w);
    }
    const float inv = 1.0f / fmaxf((float)(end - beg), 1.0f);
    ushort4 o;
    o.x = bf16_rn((a0.x + a1.x + a2.x + a3.x) * inv);
    o.y = bf16_rn((a0.y + a1.y + a2.y + a3.y) * inv);
    o.z = bf16_rn((a0.z + a1.z + a2.z + a3.z) * inv);
    o.w = bf16_rn((a0.w + a1.w + a2.w + a3.w) * inv);
    *(ushort4*)(aggbf + (size_t)gw * D + lane * 4) = o;
}

// ---------------- scores: 2 pairs per wave, 16B loads, half-wave reduce ----------------
__global__ __launch_bounds__(256) void score_kernel(
    const unsigned short* __restrict__ h,
    const int* __restrict__ pos_src, const int* __restrict__ pos_dst,
    const int* __restrict__ neg_src, const int* __restrict__ neg_dst,
    float* __restrict__ out, int EP, int N)
{
    const int gw   = (blockIdx.x * 256 + threadIdx.x) >> 6;   // wave id
    const int lane = threadIdx.x & 63;
    const int half = lane >> 5;           // 0 or 1
    const int l32  = lane & 31;
    const int pair = gw * 2 + half;
    if (pair >= 2 * EP) return;
    const int kind = pair / EP;
    const int k    = pair - kind * EP;
    const int s = kind ? neg_src[k] : pos_src[k];
    const int d = kind ? neg_dst[k] : pos_dst[k];
    const u32x4 av = *(const u32x4*)(h + (size_t)s * D + l32 * 8);
    const u32x4 bv = *(const u32x4*)(h + ((size_t)N + d) * D + l32 * 8);
    float v = 0.f;
    #pragma unroll
    for (int j = 0; j < 4; ++j) {
        const unsigned int ua = av[j], ub = bv[j];
        v += __uint_as_float(ua << 16) * __uint_as_float(ub << 16);
        v += __uint_as_float(ua & 0xFFFF0000u) * __uint_as_float(ub & 0xFFFF0000u);
    }
    v += __shfl_xor(v, 16);
    v += __shfl_xor(v, 8);
    v += __shfl_xor(v, 4);
    v += __shfl_xor(v, 2);
    v += __shfl_xor(v, 1);
    if (l32 == 0) out[pair] = v;
}

extern "C" void kernel_launch(void* const* d_in, const int* in_sizes, int n_in,
                              void* d_out, int out_size, void* d_ws, size_t ws_size,
                              hipStream_t stream)
{
    const float* x      = (const float*)d_in[0];
    const float* W_in   = (const float*)d_in[1];
    const float* b_in   = (const float*)d_in[2];
    const float* lora_A = (const float*)d_in[3];
    const float* lora_B = (const float*)d_in[4];
    const float* pn_g   = (const float*)d_in[5];
    const float* pn_b   = (const float*)d_in[6];
    const float* W_self = (const float*)d_in[7];
    const float* W_neigh= (const float*)d_in[8];
    const float* b_sage = (const float*)d_in[9];
    const float* ln_g   = (const float*)d_in[10];
    const float* ln_b   = (const float*)d_in[11];
    const float* Wv     = (const float*)d_in[12];
    const float* bvp    = (const float*)d_in[13];
    const float* Wo     = (const float*)d_in[14];
    const float* bo     = (const float*)d_in[15];
    const int* e_src    = (const int*)d_in[16];
    const int* e_dst    = (const int*)d_in[17];
    const int* pos_src  = (const int*)d_in[18];
    const int* pos_dst  = (const int*)d_in[19];
    const int* neg_src  = (const int*)d_in[20];
    const int* neg_dst  = (const int*)d_in[21];

    const int N  = in_sizes[0] / (2 * D);
    const int E  = in_sizes[16] / 2;
    const int EP = in_sizes[18];
    const size_t ND2 = (size_t)2 * N * D;
    const size_t DD2 = (size_t)2 * D * D;
    const int n2 = 2 * N;

    unsigned short* P0 = (unsigned short*)d_ws;
    unsigned short* P1 = P0 + ND2;
    unsigned short* P2 = P1 + ND2;
    unsigned short* T  = P2 + ND2;              // spare (tail-read slack)
    int* cnt    = (int*)(T + ND2);
    int* cur    = cnt + (size_t)n2;
    int* offs   = cur + (size_t)n2;             // n2+1
    int* sorted = offs + (size_t)n2 + 1;
    int* texcl  = sorted + (size_t)2 * E;
    int* bsum   = texcl + SCAN_T;
    int* bbase  = bsum + SCAN_NB;
    float* wvo  = (float*)(bbase + SCAN_NB);
    float* bvo  = wvo + DD2;
    float* b1e  = bvo + 2 * D;
    unsigned short* win_eff = (unsigned short*)(b1e + 2 * D);
    unsigned short* ws0 = win_eff + DD2;
    unsigned short* wn0 = ws0 + DD2;
    unsigned short* ws1 = wn0 + DD2;
    unsigned short* wn1 = ws1 + DD2;

    // ---- weight precompute: 2 merged dispatches ----
    pre1_kernel<<<2050, 256, 0, stream>>>(W_in, lora_A, lora_B, win_eff,
                                          W_self, ws0, W_neigh, wn0,
                                          Wo, Wv, wvo, bvp, bo, bvo);
    pre2_kernel<<<1026, 256, 0, stream>>>(wvo, W_self + DD2, ws1,
                                          W_neigh + DD2, wn1,
                                          b_sage + 2 * D, bvo, b1e);

    // ---- CSR build (edges shared by both layers) ----
    hipMemsetAsync(cnt, 0, (size_t)2 * n2 * sizeof(int), stream);
    count_kernel<<<(2 * E + 255) / 256, 256, 0, stream>>>(e_dst, cnt, 2 * E, N, E);
    const int sc = (n2 + SCAN_T - 1) / SCAN_T;
    scan1_kernel<<<SCAN_NB, 256, 0, stream>>>(cnt, texcl, bsum, n2, sc);
    scan2_kernel<<<1, 64, 0, stream>>>(bsum, bbase, offs, n2, SCAN_NB);
    scan3_kernel<<<SCAN_NB, 256, 0, stream>>>(cnt, texcl, bbase, offs, n2, sc);
    fill_kernel<<<(2 * E + 255) / 256, 256, 0, stream>>>(e_src, e_dst, offs, cur, sorted, 2 * E, N, E);

    const dim3 gblk(256);
    const int mpan = (N + 63) / 64;             // 782
    const dim3 fgrid(mpan, 1, 2);

    // ---- input projection + prenorm (fused) -> P0 ----
    gemm_ln_in_kernel<<<fgrid, gblk, 0, stream>>>(x, win_eff, b_in, pn_g, pn_b, P0, N);

    // ---- layer 0: agg(P0)->P1 ; fused GEMM+LN -> P2 ----
    agg_kernel<<<dim3((2 * N + 3) / 4, 1, 1), gblk, 0, stream>>>(P0, sorted, offs, P1, N);
    gemm_ln_kernel<<<fgrid, gblk, 0, stream>>>(P0, ws0, P1, wn0, b_sage, nullptr,
                                               ln_g, ln_b, P2, N, 1);

    // ---- layer 1 (Wv/Wo folded): agg(P2)->P1 ; fused GEMM+LN(+res=P2) -> P0 ----
    agg_kernel<<<dim3((2 * N + 3) / 4, 1, 1), gblk, 0, stream>>>(P2, sorted, offs, P1, N);
    gemm_ln_kernel<<<fgrid, gblk, 0, stream>>>(P2, ws1, P1, wn1, b1e, P2,
                                               ln_g + 2 * D, ln_b + 2 * D, P0, N, 1);

    // ---- scores: 2 pairs/wave ----
    score_kernel<<<(2 * EP + 7) / 8, gblk, 0, stream>>>(P0, pos_src, pos_dst, neg_src, neg_dst,
                                                        (float*)d_out, EP, N);
}

// Round 22
// 427.335 us; speedup vs baseline: 1.2615x; 1.0108x over previous
//
#include <hip/hip_runtime.h>

#define D 256
#define BK 64
#define SCAN_NB 64
#define SCAN_T (SCAN_NB * 256)

typedef __attribute__((ext_vector_type(8))) short bf16x8;
typedef __attribute__((ext_vector_type(4))) float f32x4;
typedef __attribute__((ext_vector_type(4))) unsigned int u32x4;

union frag_cvt { u32x4 u; bf16x8 h; };

__device__ __forceinline__ unsigned short bf16_rn(float f) {
    const unsigned int u = __float_as_uint(f);
    return (unsigned short)((u + 0x7FFFu + ((u >> 16) & 1u)) >> 16);
}
__device__ __forceinline__ float bf16_to_f32(unsigned short s) {
    return __uint_as_float(((unsigned int)s) << 16);
}

// ---------------- merged weight precompute + edge histogram, phase 1 ----------------
__global__ __launch_bounds__(256) void pre1_kernel(
    const float* __restrict__ W_in, const float* __restrict__ lA, const float* __restrict__ lB,
    unsigned short* __restrict__ win_eff,
    const float* __restrict__ W_self, unsigned short* __restrict__ ws0,
    const float* __restrict__ W_neigh, unsigned short* __restrict__ wn0,
    const float* __restrict__ Wo, const float* __restrict__ Wv, float* __restrict__ wvo,
    const float* __restrict__ bvp, const float* __restrict__ bo, float* __restrict__ bvo,
    const int* __restrict__ e_dst, int* __restrict__ cnt, int N, int E)
{
    const int b = blockIdx.x, tid = threadIdx.x;
    if (b < 512) {
        const int t = b >> 8, o = b & 255;
        float acc = W_in[((size_t)t * D + o) * D + tid];
        const float* Br = lB + ((size_t)t * D + o) * 16;
        const float* At = lA + (size_t)t * 16 * D;
        #pragma unroll
        for (int r = 0; r < 16; ++r) acc = fmaf(Br[r], At[r * D + tid], acc);
        win_eff[((size_t)t * D + o) * D + tid] = bf16_rn(acc);
    } else if (b < 1024) {
        const int i = (b - 512) * 256 + tid;
        ws0[i] = bf16_rn(W_self[i]);
    } else if (b < 1536) {
        const int i = (b - 1024) * 256 + tid;
        wn0[i] = bf16_rn(W_neigh[i]);
    } else if (b < 2048) {
        const int t = (b - 1536) >> 8, p = (b - 1536) & 255;
        const float* Xr = Wo + ((size_t)t * D + p) * D;
        const float* Yt = Wv + (size_t)t * D * D;
        float acc = 0.f;
        for (int o = 0; o < D; ++o) acc = fmaf(Xr[o], Yt[(size_t)o * D + tid], acc);
        wvo[((size_t)t * D + p) * D + tid] = acc;
    } else if (b < 2050) {
        const int t = b - 2048;
        const float* Mr = Wo + ((size_t)t * D + tid) * D;
        const float* vr = bvp + (size_t)t * D;
        float acc = bo[(size_t)t * D + tid];
        for (int o = 0; o < D; ++o) acc = fmaf(Mr[o], vr[o], acc);
        bvo[(size_t)t * D + tid] = acc;
    } else {
        const int i = (b - 2050) * 256 + tid;     // edge histogram
        if (i < 2 * E) {
            const int t = i / E;
            atomicAdd(&cnt[(size_t)t * N + e_dst[i]], 1);
        }
    }
}

// ---------------- merged weight precompute, phase 2 (needs wvo) ----------------
__global__ __launch_bounds__(256) void pre2_kernel(
    const float* __restrict__ wvo,
    const float* __restrict__ W_self1, unsigned short* __restrict__ ws1,
    const float* __restrict__ W_neigh1, unsigned short* __restrict__ wn1,
    const float* __restrict__ b_sage1, const float* __restrict__ bvo, float* __restrict__ b1e)
{
    const int b = blockIdx.x, tid = threadIdx.x;
    if (b < 512) {
        const int t = b >> 8, p = b & 255;
        const float* Xr = wvo + ((size_t)t * D + p) * D;
        const float* Yt = W_self1 + (size_t)t * D * D;
        float acc = 0.f;
        for (int o = 0; o < D; ++o) acc = fmaf(Xr[o], Yt[(size_t)o * D + tid], acc);
        ws1[((size_t)t * D + p) * D + tid] = bf16_rn(acc);
    } else if (b < 1024) {
        const int t = (b - 512) >> 8, p = (b - 512) & 255;
        const float* Xr = wvo + ((size_t)t * D + p) * D;
        const float* Yt = W_neigh1 + (size_t)t * D * D;
        float acc = 0.f;
        for (int o = 0; o < D; ++o) acc = fmaf(Xr[o], Yt[(size_t)o * D + tid], acc);
        wn1[((size_t)t * D + p) * D + tid] = bf16_rn(acc);
    } else {
        const int t = b - 1024;
        const float* Mr = wvo + ((size_t)t * D + tid) * D;
        const float* vr = b_sage1 + (size_t)t * D;
        float acc = bvo[(size_t)t * D + tid];
        for (int o = 0; o < D; ++o) acc = fmaf(Mr[o], vr[o], acc);
        b1e[(size_t)t * D + tid] = acc;
    }
}

// ---------------- B fragments for one 128-wide K-half (wave's 64-col slice) ----------------
__device__ __forceinline__ void load_bfrag(const unsigned short* __restrict__ Wp,
                                           int wn, int cidx, int rgrp,
                                           int kh, bf16x8 (&bq)[4][4])
{
    #pragma unroll
    for (int n = 0; n < 4; ++n) {
        const int o = wn + n * 16 + cidx;
        #pragma unroll
        for (int kk = 0; kk < 4; ++kk) {
            frag_cvt c;
            c.u = *(const u32x4*)(Wp + (size_t)o * D + kh * 128 + kk * 32 + rgrp * 8);
            bq[n][kk] = c.h;
        }
    }
}

// ---------------- 64-row A tile -> LDS via global_load_lds (256 thr, pre-swizzled src) ----------------
__device__ __forceinline__ void gload_tile64(const unsigned short* __restrict__ Abase,
                                             int r0, int kt, int tid, char* lbuf)
{
    const int wbase = (tid >> 6) << 10;   // wave-uniform 1KB sub-block
    #pragma unroll
    for (int c = 0; c < 2; ++c) {
        const int p   = c * 4096 + tid * 16;     // physical LDS byte offset (0..8191)
        const int row = p >> 7;                  // 128 B per row (64 bf16)
        const int lwb = p & 127;
        const int lg  = lwb ^ ((row & 7) << 4);  // logical within-row byte
        const unsigned short* g = Abase + (size_t)(r0 + row) * D + kt + (lg >> 1);
        char* l = lbuf + c * 4096 + wbase;       // wave-uniform base; HW adds lane*16
        __builtin_amdgcn_global_load_lds(
            (const __attribute__((address_space(1))) unsigned int*)g,
            (__attribute__((address_space(3))) unsigned int*)l, 16, 0, 0);
    }
}

// ---------------- fused LN epilogue: acc+bias(+res) -> LN (single-pass stats) -> bf16 out ----------------
__device__ __forceinline__ void ln_epilogue(
    f32x4 (&acc)[4][4], unsigned short* SH,
    const float* __restrict__ bias, const unsigned short* __restrict__ res_bf,
    const float* __restrict__ g, const float* __restrict__ b,
    unsigned short* __restrict__ out_bf,
    int t, int m0, int M, int tid, int wid, int rgrp, int cidx, int wn)
{
    #pragma unroll
    for (int n = 0; n < 4; ++n) {
        const float bc = bias[t * D + wn + n * 16 + cidx];
        #pragma unroll
        for (int m = 0; m < 4; ++m)
            #pragma unroll
            for (int i = 0; i < 4; ++i)
                acc[m][n][i] += bc;
    }
    if (res_bf) {
        #pragma unroll
        for (int m = 0; m < 4; ++m)
            #pragma unroll
            for (int i = 0; i < 4; ++i) {
                const int row = m * 16 + rgrp * 4 + i;
                const int gr  = min(m0 + row, M - 1);
                const unsigned short* rr = res_bf + ((size_t)t * M + gr) * D + wn + cidx;
                #pragma unroll
                for (int n = 0; n < 4; ++n)
                    acc[m][n][i] += bf16_to_f32(rr[n * 16]);
            }
    }
    float* red  = (float*)((char*)SH + 16384);   // [64][4] sums
    float* red2 = red + 256;                      // [64][4] sqsums
    float mu[4][4], rs[4][4];
    #pragma unroll
    for (int m = 0; m < 4; ++m)
        #pragma unroll
        for (int i = 0; i < 4; ++i) {
            float s = 0.f, q = 0.f;
            #pragma unroll
            for (int n = 0; n < 4; ++n) {
                const float v = acc[m][n][i];
                s += v; q += v * v;
            }
            s += __shfl_xor(s, 1); q += __shfl_xor(q, 1);
            s += __shfl_xor(s, 2); q += __shfl_xor(q, 2);
            s += __shfl_xor(s, 4); q += __shfl_xor(q, 4);
            s += __shfl_xor(s, 8); q += __shfl_xor(q, 8);
            if (cidx == 0) {
                const int row = m * 16 + rgrp * 4 + i;
                red[row * 4 + wid]  = s;
                red2[row * 4 + wid] = q;
            }
        }
    __syncthreads();
    #pragma unroll
    for (int m = 0; m < 4; ++m)
        #pragma unroll
        for (int i = 0; i < 4; ++i) {
            const int row = m * 16 + rgrp * 4 + i;
            const float S = red[row * 4] + red[row * 4 + 1] + red[row * 4 + 2] + red[row * 4 + 3];
            const float Q = red2[row * 4] + red2[row * 4 + 1] + red2[row * 4 + 2] + red2[row * 4 + 3];
            const float m_ = S * (1.0f / 256.0f);
            float var = Q * (1.0f / 256.0f) - m_ * m_;
            var = fmaxf(var, 0.f);
            mu[m][i] = m_;
            rs[m][i] = rsqrtf(var + 1e-5f);
        }
    __syncthreads();
    #pragma unroll
    for (int n = 0; n < 4; ++n) {
        const int col = wn + n * 16 + cidx;
        const float gv = g[t * D + col];
        const float bv = b[t * D + col];
        #pragma unroll
        for (int m = 0; m < 4; ++m)
            #pragma unroll
            for (int i = 0; i < 4; ++i) {
                const int row = m * 16 + rgrp * 4 + i;
                SH[row * 264 + col] = bf16_rn((acc[m][n][i] - mu[m][i]) * rs[m][i] * gv + bv);
            }
    }
    __syncthreads();
    unsigned short* Ct = out_bf + (size_t)t * M * D;
    #pragma unroll
    for (int it = 0; it < 8; ++it) {
        const int gidx = tid + it * 256;
        const int row  = gidx >> 5;
        const int cg   = gidx & 31;
        const int grow = m0 + row;
        if (grow < M) {
            const u32x4 v = *(const u32x4*)&SH[row * 264 + cg * 8];
            *(u32x4*)(Ct + (size_t)grow * D + cg * 8) = v;
        }
    }
}

// ======== fused layer GEMM+LN: out = LN( A.W1^T + A2[swap].W2^T + bias (+res) ) ========
__global__ __launch_bounds__(256, 2) void gemm_ln_kernel(
    const unsigned short* __restrict__ A, const unsigned short* __restrict__ W1,
    const unsigned short* __restrict__ A2, const unsigned short* __restrict__ W2,
    const float* __restrict__ bias, const unsigned short* __restrict__ res_bf,
    const float* __restrict__ g, const float* __restrict__ b,
    unsigned short* __restrict__ out_bf, int M, int swap2)
{
    const int t   = blockIdx.z;
    const int m0  = blockIdx.x * 64;
    const int tid = threadIdx.x;
    const int lane = tid & 63;
    const int wid  = tid >> 6;
    const int wn = wid * 64;
    const int rgrp = lane >> 4;
    const int cidx = lane & 15;

    __shared__ __align__(16) unsigned short SH[64 * 264];
    char* AsB0 = (char*)SH;
    char* AsB1 = (char*)SH + 8192;

    const int t2 = swap2 ? (1 - t) : t;
    const unsigned short* Aps[2] = { A  + (size_t)t  * M * D, A2 + (size_t)t2 * M * D };
    const unsigned short* Wps[2] = { W1 + (size_t)t  * D * D, W2 + (size_t)t  * D * D };

    f32x4 acc[4][4];
    #pragma unroll
    for (int i = 0; i < 4; ++i)
        #pragma unroll
        for (int j = 0; j < 4; ++j)
            acc[i][j] = (f32x4){0.f, 0.f, 0.f, 0.f};

    bf16x8 bq[2][4][4];
    gload_tile64(Aps[0], m0, 0, tid, AsB0);
    load_bfrag(Wps[0], wn, cidx, rgrp, 0, bq[0]);

    #pragma unroll
    for (int idx = 0; idx < 8; ++idx) {
        __syncthreads();
        if (idx < 7)
            gload_tile64(Aps[(idx + 1) >> 2], m0, ((idx + 1) & 3) * BK, tid,
                         (idx & 1) ? AsB0 : AsB1);
        if ((idx & 1) == 1 && idx < 7) {
            const int nh = (idx >> 1) + 1;
            load_bfrag(Wps[nh >> 1], wn, cidx, rgrp, nh & 1, bq[nh & 1]);
        }
        const char* cb = (idx & 1) ? AsB1 : AsB0;
        const int half = idx >> 1;
        #pragma unroll
        for (int ks = 0; ks < 2; ++ks) {
            const int kb = ks * 64 + rgrp * 16;
            bf16x8 af[4];
            #pragma unroll
            for (int m = 0; m < 4; ++m) {
                const int row = m * 16 + cidx;
                const int sw  = (row * 128 + kb) ^ ((row & 7) << 4);
                frag_cvt c; c.u = *(const u32x4*)(cb + sw); af[m] = c.h;
            }
            #pragma unroll
            for (int m = 0; m < 4; ++m)
                #pragma unroll
                for (int n = 0; n < 4; ++n)
                    acc[m][n] = __builtin_amdgcn_mfma_f32_16x16x32_bf16(
                        af[m], bq[half & 1][n][(idx & 1) * 2 + ks], acc[m][n], 0, 0, 0);
        }
        __syncthreads();
    }

    ln_epilogue(acc, SH, bias, res_bf, g, b, out_bf, t, m0, M, tid, wid, rgrp, cidx, wn);
}

// ======== fused input GEMM+LN: out = LN( bf16(X).W^T + bias ) ========
__global__ __launch_bounds__(256, 2) void gemm_ln_in_kernel(
    const float* __restrict__ X, const unsigned short* __restrict__ Wb,
    const float* __restrict__ bias,
    const float* __restrict__ g, const float* __restrict__ b,
    unsigned short* __restrict__ out_bf, int M)
{
    const int t   = blockIdx.z;
    const int m0  = blockIdx.x * 64;
    const int tid = threadIdx.x;
    const int lane = tid & 63;
    const int wid  = tid >> 6;
    const int wn = wid * 64;
    const int rgrp = lane >> 4;
    const int cidx = lane & 15;

    __shared__ __align__(16) unsigned short SH[64 * 264];
    char* AsB = (char*)SH;

    const float* Xp = X + (size_t)t * M * D;
    const unsigned short* Wp = Wb + (size_t)t * D * D;

    f32x4 acc[4][4];
    #pragma unroll
    for (int i = 0; i < 4; ++i)
        #pragma unroll
        for (int j = 0; j < 4; ++j)
            acc[i][j] = (f32x4){0.f, 0.f, 0.f, 0.f};

    bf16x8 bq[2][4][4];
    float4 xr0[2], xr1[2];
    #pragma unroll
    for (int it = 0; it < 2; ++it) {
        const int gi = tid + it * 256;
        const int row = gi >> 3;
        const int kg = gi & 7;
        const int ar = min(m0 + row, M - 1);
        xr0[it] = *(const float4*)(Xp + (size_t)ar * D + kg * 8);
        xr1[it] = *(const float4*)(Xp + (size_t)ar * D + kg * 8 + 4);
    }
    load_bfrag(Wp, wn, cidx, rgrp, 0, bq[0]);

    #pragma unroll
    for (int kt_i = 0; kt_i < 4; ++kt_i) {
        #pragma unroll
        for (int it = 0; it < 2; ++it) {
            const int gi = tid + it * 256;
            const int row = gi >> 3;
            const int kg = gi & 7;
            unsigned int w[4];
            w[0] = ((unsigned int)bf16_rn(xr0[it].y) << 16) | bf16_rn(xr0[it].x);
            w[1] = ((unsigned int)bf16_rn(xr0[it].w) << 16) | bf16_rn(xr0[it].z);
            w[2] = ((unsigned int)bf16_rn(xr1[it].y) << 16) | bf16_rn(xr1[it].x);
            w[3] = ((unsigned int)bf16_rn(xr1[it].w) << 16) | bf16_rn(xr1[it].z);
            const int sw = ((row * BK + kg * 8) * 2) ^ ((row & 7) << 4);
            *(u32x4*)(AsB + sw) = (u32x4){w[0], w[1], w[2], w[3]};
        }
        __syncthreads();
        if (kt_i < 3) {
            const int kt = (kt_i + 1) * BK;
            #pragma unroll
            for (int it = 0; it < 2; ++it) {
                const int gi = tid + it * 256;
                const int row = gi >> 3;
                const int kg = gi & 7;
                const int ar = min(m0 + row, M - 1);
                xr0[it] = *(const float4*)(Xp + (size_t)ar * D + kt + kg * 8);
                xr1[it] = *(const float4*)(Xp + (size_t)ar * D + kt + kg * 8 + 4);
            }
        }
        if (kt_i == 1) load_bfrag(Wp, wn, cidx, rgrp, 1, bq[1]);
        #pragma unroll
        for (int ks = 0; ks < 2; ++ks) {
            const int kb = ks * 64 + rgrp * 16;
            bf16x8 af[4];
            #pragma unroll
            for (int m = 0; m < 4; ++m) {
                const int row = m * 16 + cidx;
                const int sw  = (row * 128 + kb) ^ ((row & 7) << 4);
                frag_cvt c; c.u = *(u32x4*)(AsB + sw); af[m] = c.h;
            }
            #pragma unroll
            for (int m = 0; m < 4; ++m)
                #pragma unroll
                for (int n = 0; n < 4; ++n)
                    acc[m][n] = __builtin_amdgcn_mfma_f32_16x16x32_bf16(
                        af[m], bq[kt_i >> 1][n][(kt_i & 1) * 2 + ks], acc[m][n], 0, 0, 0);
        }
        __syncthreads();
    }

    ln_epilogue(acc, SH, bias, nullptr, g, b, out_bf, t, m0, M, tid, wid, rgrp, cidx, wn);
}

// ---------------- CSR scan + fill ----------------
__global__ __launch_bounds__(256) void scan1_kernel(const int* __restrict__ cnt,
                                                    int* __restrict__ texcl,
                                                    int* __restrict__ bsum, int n, int c)
{
    __shared__ int ts[256];
    const int tid = threadIdx.x;
    const int gt  = blockIdx.x * 256 + tid;
    const int b   = gt * c;
    const int e   = min(b + c, n);
    int s = 0;
    for (int i = b; i < e; ++i) s += cnt[i];
    ts[tid] = s;
    __syncthreads();
    #pragma unroll
    for (int off = 1; off < 256; off <<= 1) {
        const int v = (tid >= off) ? ts[tid - off] : 0;
        __syncthreads();
        ts[tid] += v;
        __syncthreads();
    }
    texcl[gt] = ts[tid] - s;
    if (tid == 255) bsum[blockIdx.x] = ts[255];
}

__global__ __launch_bounds__(64) void scan2_kernel(int* __restrict__ bsum,
                                                   int* __restrict__ bbase,
                                                   int* __restrict__ offs, int n, int nb)
{
    const int lane = threadIdx.x;
    int v = (lane < nb) ? bsum[lane] : 0;
    int s = v;
    #pragma unroll
    for (int off = 1; off < 64; off <<= 1) {
        const int u = __shfl_up(s, off);
        if (lane >= off) s += u;
    }
    if (lane < nb) bbase[lane] = s - v;
    if (lane == 63) offs[n] = s;
}

__global__ __launch_bounds__(256) void scan3_kernel(const int* __restrict__ cnt,
                                                    const int* __restrict__ texcl,
                                                    const int* __restrict__ bbase,
                                                    int* __restrict__ offs, int n, int c)
{
    const int tid = threadIdx.x;
    const int gt  = blockIdx.x * 256 + tid;
    const int b   = gt * c;
    const int e   = min(b + c, n);
    int base = bbase[blockIdx.x] + texcl[gt];
    for (int i = b; i < e; ++i) { offs[i] = base; base += cnt[i]; }
}

__global__ void fill_kernel(const int* __restrict__ e_src, const int* __restrict__ e_dst,
                            const int* __restrict__ offs, int* __restrict__ cur,
                            int* __restrict__ sorted, int E2, int N, int E)
{
    const int i = blockIdx.x * 256 + threadIdx.x;
    if (i >= E2) return;
    const int t = i / E;
    const int idx = t * N + e_dst[i];
    const int pos = offs[idx] + atomicAdd(&cur[idx], 1);
    sorted[pos] = e_src[i];
}

// ---------------- aggregation: half-wave per (t,dst), 16B gathers, 4-way MLP ----------------
__global__ __launch_bounds__(256) void agg_kernel(
    const unsigned short* __restrict__ hbf, const int* __restrict__ sorted_src,
    const int* __restrict__ offs, unsigned short* __restrict__ aggbf, int N)
{
    const int ghw = (blockIdx.x * 256 + threadIdx.x) >> 5;   // half-wave id
    const int l32 = threadIdx.x & 31;
    if (ghw >= 2 * N) return;
    const int t = (ghw >= N) ? 1 : 0;
    const int beg = offs[ghw];
    const int end = offs[ghw + 1];
    const unsigned short* hb = hbf + (size_t)t * N * D;
    float a[4][8];
    #pragma unroll
    for (int w = 0; w < 4; ++w)
        #pragma unroll
        for (int j = 0; j < 8; ++j) a[w][j] = 0.f;
    int e = beg;
    for (; e + 4 <= end; e += 4) {
        const int s0 = sorted_src[e];
        const int s1 = sorted_src[e + 1];
        const int s2 = sorted_src[e + 2];
        const int s3 = sorted_src[e + 3];
        const u32x4 v0 = *(const u32x4*)(hb + (size_t)s0 * D + l32 * 8);
        const u32x4 v1 = *(const u32x4*)(hb + (size_t)s1 * D + l32 * 8);
        const u32x4 v2 = *(const u32x4*)(hb + (size_t)s2 * D + l32 * 8);
        const u32x4 v3 = *(const u32x4*)(hb + (size_t)s3 * D + l32 * 8);
        #pragma unroll
        for (int j = 0; j < 4; ++j) {
            a[0][2*j]   += __uint_as_float(v0[j] << 16);
            a[0][2*j+1] += __uint_as_float(v0[j] & 0xFFFF0000u);
            a[1][2*j]   += __uint_as_float(v1[j] << 16);
            a[1][2*j+1] += __uint_as_float(v1[j] & 0xFFFF0000u);
            a[2][2*j]   += __uint_as_float(v2[j] << 16);
            a[2][2*j+1] += __uint_as_float(v2[j] & 0xFFFF0000u);
            a[3][2*j]   += __uint_as_float(v3[j] << 16);
            a[3][2*j+1] += __uint_as_float(v3[j] & 0xFFFF0000u);
        }
    }
    for (; e < end; ++e) {
        const int s0 = sorted_src[e];
        const u32x4 v0 = *(const u32x4*)(hb + (size_t)s0 * D + l32 * 8);
        #pragma unroll
        for (int j = 0; j < 4; ++j) {
            a[0][2*j]   += __uint_as_float(v0[j] << 16);
            a[0][2*j+1] += __uint_as_float(v0[j] & 0xFFFF0000u);
        }
    }
    const float inv = 1.0f / fmaxf((float)(end - beg), 1.0f);
    u32x4 o;
    #pragma unroll
    for (int j = 0; j < 4; ++j) {
        const float lo = (a[0][2*j]   + a[1][2*j]   + a[2][2*j]   + a[3][2*j])   * inv;
        const float hi = (a[0][2*j+1] + a[1][2*j+1] + a[2][2*j+1] + a[3][2*j+1]) * inv;
        o[j] = ((unsigned int)bf16_rn(hi) << 16) | bf16_rn(lo);
    }
    *(u32x4*)(aggbf + (size_t)ghw * D + l32 * 8) = o;
}

// ---------------- scores: 2 pairs per wave, 16B loads, half-wave reduce ----------------
__global__ __launch_bounds__(256) void score_kernel(
    const unsigned short* __restrict__ h,
    const int* __restrict__ pos_src, const int* __restrict__ pos_dst,
    const int* __restrict__ neg_src, const int* __restrict__ neg_dst,
    float* __restrict__ out, int EP, int N)
{
    const int gw   = (blockIdx.x * 256 + threadIdx.x) >> 6;
    const int lane = threadIdx.x & 63;
    const int half = lane >> 5;
    const int l32  = lane & 31;
    const int pair = gw * 2 + half;
    if (pair >= 2 * EP) return;
    const int kind = pair / EP;
    const int k    = pair - kind * EP;
    const int s = kind ? neg_src[k] : pos_src[k];
    const int d = kind ? neg_dst[k] : pos_dst[k];
    const u32x4 av = *(const u32x4*)(h + (size_t)s * D + l32 * 8);
    const u32x4 bv = *(const u32x4*)(h + ((size_t)N + d) * D + l32 * 8);
    float v = 0.f;
    #pragma unroll
    for (int j = 0; j < 4; ++j) {
        const unsigned int ua = av[j], ub = bv[j];
        v += __uint_as_float(ua << 16) * __uint_as_float(ub << 16);
        v += __uint_as_float(ua & 0xFFFF0000u) * __uint_as_float(ub & 0xFFFF0000u);
    }
    v += __shfl_xor(v, 16);
    v += __shfl_xor(v, 8);
    v += __shfl_xor(v, 4);
    v += __shfl_xor(v, 2);
    v += __shfl_xor(v, 1);
    if (l32 == 0) out[pair] = v;
}

extern "C" void kernel_launch(void* const* d_in, const int* in_sizes, int n_in,
                              void* d_out, int out_size, void* d_ws, size_t ws_size,
                              hipStream_t stream)
{
    const float* x      = (const float*)d_in[0];
    const float* W_in   = (const float*)d_in[1];
    const float* b_in   = (const float*)d_in[2];
    const float* lora_A = (const float*)d_in[3];
    const float* lora_B = (const float*)d_in[4];
    const float* pn_g   = (const float*)d_in[5];
    const float* pn_b   = (const float*)d_in[6];
    const float* W_self = (const float*)d_in[7];
    const float* W_neigh= (const float*)d_in[8];
    const float* b_sage = (const float*)d_in[9];
    const float* ln_g   = (const float*)d_in[10];
    const float* ln_b   = (const float*)d_in[11];
    const float* Wv     = (const float*)d_in[12];
    const float* bvp    = (const float*)d_in[13];
    const float* Wo     = (const float*)d_in[14];
    const float* bo     = (const float*)d_in[15];
    const int* e_src    = (const int*)d_in[16];
    const int* e_dst    = (const int*)d_in[17];
    const int* pos_src  = (const int*)d_in[18];
    const int* pos_dst  = (const int*)d_in[19];
    const int* neg_src  = (const int*)d_in[20];
    const int* neg_dst  = (const int*)d_in[21];

    const int N  = in_sizes[0] / (2 * D);
    const int E  = in_sizes[16] / 2;
    const int EP = in_sizes[18];
    const size_t ND2 = (size_t)2 * N * D;
    const size_t DD2 = (size_t)2 * D * D;
    const int n2 = 2 * N;

    unsigned short* P0 = (unsigned short*)d_ws;
    unsigned short* P1 = P0 + ND2;
    unsigned short* P2 = P1 + ND2;
    unsigned short* T  = P2 + ND2;              // spare (tail-read slack)
    int* cnt    = (int*)(T + ND2);
    int* cur    = cnt + (size_t)n2;
    int* offs   = cur + (size_t)n2;             // n2+1
    int* sorted = offs + (size_t)n2 + 1;
    int* texcl  = sorted + (size_t)2 * E;
    int* bsum   = texcl + SCAN_T;
    int* bbase  = bsum + SCAN_NB;
    float* wvo  = (float*)(bbase + SCAN_NB);
    float* bvo  = wvo + DD2;
    float* b1e  = bvo + 2 * D;
    unsigned short* win_eff = (unsigned short*)(b1e + 2 * D);
    unsigned short* ws0 = win_eff + DD2;
    unsigned short* wn0 = ws0 + DD2;
    unsigned short* ws1 = wn0 + DD2;
    unsigned short* wn1 = ws1 + DD2;

    // ---- memset cnt+cur first, then merged precompute+histogram ----
    hipMemsetAsync(cnt, 0, (size_t)2 * n2 * sizeof(int), stream);
    const int cnt_blocks = (2 * E + 255) / 256;
    pre1_kernel<<<2050 + cnt_blocks, 256, 0, stream>>>(W_in, lora_A, lora_B, win_eff,
                                                       W_self, ws0, W_neigh, wn0,
                                                       Wo, Wv, wvo, bvp, bo, bvo,
                                                       e_dst, cnt, N, E);
    pre2_kernel<<<1026, 256, 0, stream>>>(wvo, W_self + DD2, ws1,
                                          W_neigh + DD2, wn1,
                                          b_sage + 2 * D, bvo, b1e);

    // ---- CSR scan + fill ----
    const int sc = (n2 + SCAN_T - 1) / SCAN_T;
    scan1_kernel<<<SCAN_NB, 256, 0, stream>>>(cnt, texcl, bsum, n2, sc);
    scan2_kernel<<<1, 64, 0, stream>>>(bsum, bbase, offs, n2, SCAN_NB);
    scan3_kernel<<<SCAN_NB, 256, 0, stream>>>(cnt, texcl, bbase, offs, n2, sc);
    fill_kernel<<<(2 * E + 255) / 256, 256, 0, stream>>>(e_src, e_dst, offs, cur, sorted, 2 * E, N, E);

    const dim3 gblk(256);
    const int mpan = (N + 63) / 64;             // 782
    const dim3 fgrid(mpan, 1, 2);

    // ---- input projection + prenorm (fused) -> P0 ----
    gemm_ln_in_kernel<<<fgrid, gblk, 0, stream>>>(x, win_eff, b_in, pn_g, pn_b, P0, N);

    // ---- layer 0: agg(P0)->P1 ; fused GEMM+LN -> P2 ----
    agg_kernel<<<dim3((2 * N + 7) / 8, 1, 1), gblk, 0, stream>>>(P0, sorted, offs, P1, N);
    gemm_ln_kernel<<<fgrid, gblk, 0, stream>>>(P0, ws0, P1, wn0, b_sage, nullptr,
                                               ln_g, ln_b, P2, N, 1);

    // ---- layer 1 (Wv/Wo folded): agg(P2)->P1 ; fused GEMM+LN(+res=P2) -> P0 ----
    agg_kernel<<<dim3((2 * N + 7) / 8, 1, 1), gblk, 0, stream>>>(P2, sorted, offs, P1, N);
    gemm_ln_kernel<<<fgrid, gblk, 0, stream>>>(P2, ws1, P1, wn1, b1e, P2,
                                               ln_g + 2 * D, ln_b + 2 * D, P0, N, 1);

    // ---- scores: 2 pairs/wave ----
    score_kernel<<<(2 * EP + 7) / 8, gblk, 0, stream>>>(P0, pos_src, pos_dst, neg_src, neg_dst,
                                                        (float*)d_out, EP, N);
}